// Round 3
// baseline (367.399 us; speedup 1.0000x reference)
//
#include <hip/hip_runtime.h>
#include <math.h>

// Problem constants:
//   WH=WW=16, N=256 tokens/window, H=6 heads, DIM=192, hd=32
//   B_=256 windows, nW=64 mask windows, qk_scale = 32^-0.5
#define N_TOK 256
#define NHEADS 6
#define DIM_C 192
#define HD 32
#define B_WIN 256

typedef short bf16x8 __attribute__((ext_vector_type(8)));   // 8 bf16 in 4 VGPRs
typedef float f32x4 __attribute__((ext_vector_type(4)));

__device__ inline short f2bf(float f) {          // RNE
    unsigned u = __float_as_uint(f);
    u = (u + 0x7fffu + ((u >> 16) & 1u)) >> 16;
    return (short)u;
}
__device__ inline short f2bf_fast(float f) {     // round-half-up (0.5 ulp)
    return (short)((__float_as_uint(f) + 0x8000u) >> 16);
}
__device__ inline float bf2f(short s) {
    return __uint_as_float(((unsigned)(unsigned short)s) << 16);
}

// ---------------------------------------------------------------------------
// Kernel 1: CPB MLP -> table (961 x 6) fp32
// ---------------------------------------------------------------------------
__global__ __launch_bounds__(512) void cpb_table_kernel(
    const float* __restrict__ scale, const float* __restrict__ w1,
    const float* __restrict__ b1, const float* __restrict__ w2,
    const float* __restrict__ b2, float* __restrict__ table)
{
    __shared__ float red[512];
    const int e = blockIdx.x;            // 0..960
    const int i = e / 31, j = e % 31;
    const float t0 = ((float)(i - 15)) * (8.0f / 15.0f);
    const float t1 = ((float)(j - 15)) * (8.0f / 15.0f);
    const float s0 = scale[0], s1 = scale[1];
    const int t = threadIdx.x;
    const float* w = w1 + t * 4;
    float h = w[0] * t0 + w[1] * t1 + w[2] * s0 + w[3] * s1 + b1[t];
    h = fmaxf(h, 0.0f);
    for (int head = 0; head < NHEADS; ++head) {
        red[t] = h * w2[head * 512 + t];
        __syncthreads();
        for (int s = 256; s > 0; s >>= 1) {
            if (t < s) red[t] += red[t + s];
            __syncthreads();
        }
        if (t == 0) table[e * NHEADS + head] = red[0] + b2[head];
        __syncthreads();
    }
}

// ---------------------------------------------------------------------------
// MFMA-C-layout permuted index helper. Slab layout (65536 bf16):
//   offset = ((rb*8 + g)*64 + lane)*8 + (nt&1)*4 + r
//   where row = rb*16 + (lane>>4)*4 + r,  col = nt*16 + (lane&15),  nt = 2g+(j>>2)
// Thread j in [0,8): nt = 2g + (j>>2), r = j&3.
// ---------------------------------------------------------------------------

// Kernel 2a: bias -> permuted bf16 (6 slabs). One thread per 8 outputs.
__global__ __launch_bounds__(256) void bias_perm_kernel(
    const float* __restrict__ table, short* __restrict__ bias_p)
{
    const int idx8 = blockIdx.x * 256 + threadIdx.x;   // < 6*8192
    const int h = idx8 >> 13;
    const int rem = idx8 & 8191;
    const int rb = rem >> 9;
    const int g = (rem >> 6) & 7;
    const int lane = rem & 63;
    const int quad = lane >> 4, l15 = lane & 15;
    bf16x8 o;
#pragma unroll
    for (int j = 0; j < 8; ++j) {
        const int nt = g * 2 + (j >> 2), r = j & 3;
        const int row = rb * 16 + quad * 4 + r;
        const int col = nt * 16 + l15;
        const int rel0 = (row >> 4) - (col >> 4) + 15;
        const int rel1 = (row & 15) - (col & 15) + 15;
        o[j] = f2bf(table[(rel0 * 31 + rel1) * NHEADS + h]);
    }
    ((bf16x8*)bias_p)[idx8] = o;
}

// Kernel 2b: mask -> permuted bf16 (64 slabs).
__global__ __launch_bounds__(256) void mask_perm_kernel(
    const float* __restrict__ mask, short* __restrict__ mask_p)
{
    const int idx8 = blockIdx.x * 256 + threadIdx.x;   // < 64*8192
    const int bw = idx8 >> 13;
    const int rem = idx8 & 8191;
    const int rb = rem >> 9;
    const int g = (rem >> 6) & 7;
    const int lane = rem & 63;
    const int quad = lane >> 4, l15 = lane & 15;
    const float* ms = mask + ((size_t)bw << 16);
    bf16x8 o;
#pragma unroll
    for (int j = 0; j < 8; ++j) {
        const int nt = g * 2 + (j >> 2), r = j & 3;
        const int row = rb * 16 + quad * 4 + r;
        const int col = nt * 16 + l15;
        o[j] = f2bf(ms[row * 256 + col]);
    }
    ((bf16x8*)mask_p)[idx8] = o;
}

// ---------------------------------------------------------------------------
// Kernel 2c: generic fp32 -> bf16 (n4 = count/4)  [weights only]
// ---------------------------------------------------------------------------
__global__ __launch_bounds__(256) void f32_to_bf16_kernel(
    const float* __restrict__ in, short* __restrict__ out, int n4)
{
    const int i = blockIdx.x * 256 + threadIdx.x;
    if (i < n4) {
        float4 v = ((const float4*)in)[i];
        short4 s;
        s.x = f2bf(v.x); s.y = f2bf(v.y); s.z = f2bf(v.z); s.w = f2bf(v.w);
        ((short4*)out)[i] = s;
    }
}

// ---------------------------------------------------------------------------
// Kernel 3: QKV GEMM. Grid = 3072 blocks: 3 column groups (q/k/v) x 1024
// 64-row panels. Each block stages its A panel (fp32 -> bf16 fused) in LDS
// once and computes 3 n-tiles (192 cols = its whole output tensor slice).
// R2 post-mortem: 1024 blocks grid-capped occupancy at 40% and the 9-tile
// serial loop couldn't hide W-load latency. 3x more blocks lifts the cap to
// the LDS limit (6 blocks/CU -> 24 waves/CU) and shortens the serial chain.
// XCD-chunked mapping: the 3 blocks sharing an A panel are consecutive on
// the SAME XCD -> panel is L2-hot for 2 of 3 reads.
// ---------------------------------------------------------------------------
__global__ __launch_bounds__(256) void qkv_gemm_kernel(
    const float* __restrict__ x, const short* __restrict__ w16,
    const float* __restrict__ qkv_b,
    short* __restrict__ qb, short* __restrict__ kb, short* __restrict__ vb)
{
    __shared__ __align__(16) short A[64][200];
    const int t = threadIdx.x;
    const int lane = t & 63;
    const int w = t >> 6;            // wave 0..3 -> rows w*16..w*16+15
    const int l15 = lane & 15, quad = lane >> 4;

    // block decode: xcd-chunked, 3 consecutive blocks per panel on one XCD
    const int blk = blockIdx.x;          // 0..3071
    const int xcd = blk & 7;
    const int idx = blk >> 3;            // 0..383
    const int which = idx % 3;           // 0=q,1=k,2=v
    const int y = (idx / 3) * 8 + xcd;   // 0..1023
    const int m0 = y * 64;

    // stage A: 64 rows x 192 cols fp32 -> bf16. 4 threads/row, 48 floats each.
    {
        const int row = t >> 2, p = t & 3;
        const float4* src = (const float4*)(x + (size_t)(m0 + row) * DIM_C + p * 48);
#pragma unroll
        for (int j = 0; j < 6; ++j) {
            float4 v0 = src[j * 2];
            float4 v1 = src[j * 2 + 1];
            bf16x8 o;
            o[0] = f2bf(v0.x); o[1] = f2bf(v0.y); o[2] = f2bf(v0.z); o[3] = f2bf(v0.w);
            o[4] = f2bf(v1.x); o[5] = f2bf(v1.y); o[6] = f2bf(v1.z); o[7] = f2bf(v1.w);
            *(bf16x8*)&A[row][p * 48 + j * 8] = o;
        }
    }
    __syncthreads();

    const int rowA = w * 16 + l15;
    short* outp = (which == 0) ? qb : (which == 1) ? kb : vb;
    const float qscale = (which == 0) ? 0.17677669529663689f : 1.0f;

#pragma unroll
    for (int j = 0; j < 3; ++j) {
        const int n0 = which * DIM_C + j * 64;
        f32x4 acc[4] = {};
#pragma unroll
        for (int ks = 0; ks < 6; ++ks) {
            const bf16x8 af = *(const bf16x8*)&A[rowA][ks * 32 + quad * 8];
#pragma unroll
            for (int c4 = 0; c4 < 4; ++c4) {
                const bf16x8 bfr = *(const bf16x8*)(w16 + (size_t)(n0 + c4 * 16 + l15) * DIM_C + ks * 32 + quad * 8);
                acc[c4] = __builtin_amdgcn_mfma_f32_16x16x32_bf16(af, bfr, acc[c4], 0, 0, 0);
            }
        }

#pragma unroll
        for (int r = 0; r < 4; ++r) {
            const int m = m0 + w * 16 + quad * 4 + r;
            const int b = m >> 8, tok = m & 255;
#pragma unroll
            for (int c4 = 0; c4 < 4; ++c4) {
                const int rem = j * 64 + c4 * 16 + l15;       // 0..191
                const int h = rem >> 5, d = rem & 31;
                const float val = (acc[c4][r] + qkv_b[which * DIM_C + rem]) * qscale;
                outp[((size_t)((b * NHEADS + h) * N_TOK + tok)) * HD + d] = f2bf(val);
            }
        }
    }
}

// ---------------------------------------------------------------------------
// Kernel 5: proj GEMM, one-panel-per-block. A (ao, bf16) staged in LDS once,
// reused across the 3 n-tiles. fp32 out (4B/lane coalesced stores).
// ---------------------------------------------------------------------------
__global__ __launch_bounds__(256) void proj_gemm_kernel(
    const short* __restrict__ A16, const short* __restrict__ w16,
    const float* __restrict__ proj_b, float* __restrict__ out)
{
    __shared__ __align__(16) short A[64][200];
    const int t = threadIdx.x;
    const int lane = t & 63;
    const int w = t >> 6;
    const int l15 = lane & 15, quad = lane >> 4;
    const int m0 = blockIdx.x * 64;

    // stage A: 64 rows x 192 bf16. 4 threads/row, 48 shorts each (6 x b128).
    {
        const int row = t >> 2, p = t & 3;
        const bf16x8* src = (const bf16x8*)(A16 + (size_t)(m0 + row) * DIM_C + p * 48);
#pragma unroll
        for (int j = 0; j < 6; ++j)
            *(bf16x8*)&A[row][p * 48 + j * 8] = src[j];
    }
    __syncthreads();

    const int rowA = w * 16 + l15;

#pragma unroll
    for (int nt = 0; nt < 3; ++nt) {
        const int n0 = nt * 64;
        f32x4 acc[4] = {};
#pragma unroll
        for (int ks = 0; ks < 6; ++ks) {
            const bf16x8 af = *(const bf16x8*)&A[rowA][ks * 32 + quad * 8];
#pragma unroll
            for (int c4 = 0; c4 < 4; ++c4) {
                const bf16x8 bfr = *(const bf16x8*)(w16 + (size_t)(n0 + c4 * 16 + l15) * DIM_C + ks * 32 + quad * 8);
                acc[c4] = __builtin_amdgcn_mfma_f32_16x16x32_bf16(af, bfr, acc[c4], 0, 0, 0);
            }
        }
#pragma unroll
        for (int r = 0; r < 4; ++r) {
            const int m = m0 + w * 16 + quad * 4 + r;
#pragma unroll
            for (int c4 = 0; c4 < 4; ++c4) {
                const int c = n0 + c4 * 16 + l15;
                out[(size_t)m * DIM_C + c] = acc[c4][r] + proj_b[c];
            }
        }
    }
}

// ---------------------------------------------------------------------------
// Kernel 4: MFMA attention per (b,h), wave-owns-rows structure.
//  - 1D grid + XCD-aware swizzle: all 24 blocks sharing a mask slab (bw)
//    run consecutively on one XCD.
//  - K fragments hoisted into registers once per block (chunk-invariant).
//  - bias+mask fed as the MFMA C operand (pre-permuted tables).
// ---------------------------------------------------------------------------
#define PS_LD 264   // shorts; 528 B/row (16B aligned)

__global__ __launch_bounds__(256, 3) void attn_mfma_kernel(
    const short* __restrict__ q, const short* __restrict__ k,
    const short* __restrict__ v, const short* __restrict__ bias_p,
    const short* __restrict__ mask_p, short* __restrict__ out16)
{
    __shared__ __align__(16) short Vt[32][PS_LD];      // V^T, 16.9 KB
    __shared__ __align__(16) short Pw[4][16][PS_LD];   // per-wave P, 33.8 KB

    // XCD-aware swizzle (bijective on 1536 = 8 xcd * 8 bw-groups * 24 jobs)
    const int l = blockIdx.x;            // 0..1535
    const int s = l >> 3;                // 0..191
    const int bw = (l & 7) + 8 * (s / 24);
    const int j = s % 24;
    const int h = j % 6;                 // 0..5
    const int b = (j / 6) * 64 + bw;     // 0..255

    const int t = threadIdx.x;
    const int lane = t & 63;
    const int w = t >> 6;
    const int l15 = lane & 15;
    const int quad = lane >> 4;
    const size_t slab = ((size_t)(b * NHEADS + h)) * (N_TOK * HD);

    // stage V^T (thread t -> token t), swizzled columns
    {
        const bf16x8* vrow = (const bf16x8*)(v + slab + (size_t)t * HD);
#pragma unroll
        for (int u = 0; u < 4; ++u) {
            bf16x8 vv = vrow[u];
#pragma unroll
            for (int jj = 0; jj < 8; ++jj) {
                const int d = u * 8 + jj;
                Vt[d][t ^ (((d >> 3) & 1) * 16)] = vv[jj];
            }
        }
    }

    // K fragments: chunk-invariant, load once (16 x bf16x8 = 64 VGPRs)
    bf16x8 kfr[16];
#pragma unroll
    for (int nt = 0; nt < 16; ++nt)
        kfr[nt] = *(const bf16x8*)(k + slab + (size_t)(nt * 16 + l15) * HD + quad * 8);

    __syncthreads();   // Vt ready (only barrier in the kernel body)

    const short* bslab = bias_p + h * 65536;
    const short* mslab = mask_p + bw * 65536;

    for (int chunk = 0; chunk < 4; ++chunk) {
        const int rb = chunk * 4 + w;    // row block 0..15

        // Q fragment: rows rb*16 + l15, k = quad*8..+7
        const bf16x8 qf = *(const bf16x8*)(q + slab + (size_t)(rb * 16 + l15) * HD + quad * 8);

        // QK^T with bias+mask injected as C:
        // C-layout: row = rb*16+quad*4+r, col = nt*16+l15
        f32x4 S[16];
#pragma unroll
        for (int half = 0; half < 2; ++half) {
            bf16x8 bb[4], mm[4];
#pragma unroll
            for (int gg = 0; gg < 4; ++gg) {
                const int g = half * 4 + gg;
                const int off = ((rb * 8 + g) * 64 + lane) * 8;
                bb[gg] = *(const bf16x8*)(bslab + off);
                mm[gg] = *(const bf16x8*)(mslab + off);
            }
#pragma unroll
            for (int gg = 0; gg < 4; ++gg) {
                const int g = half * 4 + gg;
                f32x4 c0, c1;
#pragma unroll
                for (int r = 0; r < 4; ++r) {
                    c0[r] = bf2f(bb[gg][r])     + bf2f(mm[gg][r]);
                    c1[r] = bf2f(bb[gg][4 + r]) + bf2f(mm[gg][4 + r]);
                }
                S[g * 2]     = __builtin_amdgcn_mfma_f32_16x16x32_bf16(qf, kfr[g * 2],     c0, 0, 0, 0);
                S[g * 2 + 1] = __builtin_amdgcn_mfma_f32_16x16x32_bf16(qf, kfr[g * 2 + 1], c1, 0, 0, 0);
            }
        }

        // row max over register tiles, then across l15 lanes
        float mx[4] = {-1e30f, -1e30f, -1e30f, -1e30f};
#pragma unroll
        for (int nt = 0; nt < 16; ++nt)
#pragma unroll
            for (int r = 0; r < 4; ++r)
                mx[r] = fmaxf(mx[r], S[nt][r]);
#pragma unroll
        for (int r = 0; r < 4; ++r) {
            mx[r] = fmaxf(mx[r], __shfl_xor(mx[r], 1));
            mx[r] = fmaxf(mx[r], __shfl_xor(mx[r], 2));
            mx[r] = fmaxf(mx[r], __shfl_xor(mx[r], 4));
            mx[r] = fmaxf(mx[r], __shfl_xor(mx[r], 8));
        }

        // exp + row sum + P -> per-wave LDS (swizzled)
        float sm[4] = {0.f, 0.f, 0.f, 0.f};
#pragma unroll
        for (int nt = 0; nt < 16; ++nt) {
#pragma unroll
            for (int r = 0; r < 4; ++r) {
                const float p = __expf(S[nt][r] - mx[r]);
                sm[r] += p;
                const int lr = quad * 4 + r;
                Pw[w][lr][(nt * 16 + l15) ^ (((lr >> 3) & 1) * 16)] = f2bf_fast(p);
            }
        }
        float inv[4];
#pragma unroll
        for (int r = 0; r < 4; ++r) {
            sm[r] += __shfl_xor(sm[r], 1);
            sm[r] += __shfl_xor(sm[r], 2);
            sm[r] += __shfl_xor(sm[r], 4);
            sm[r] += __shfl_xor(sm[r], 8);
            inv[r] = __builtin_amdgcn_rcpf(sm[r]);
        }

        // wave-local LDS: drain writes before fragment reads
        __asm__ volatile("s_waitcnt lgkmcnt(0)" ::: "memory");

        // PV: O (16 rows x 32 d), A-frags from own Pw, B-frags from Vt
        f32x4 O0 = {0.f, 0.f, 0.f, 0.f};
        f32x4 O1 = {0.f, 0.f, 0.f, 0.f};
        const int sw = ((l15 >> 3) & 1) * 16;
#pragma unroll
        for (int ks = 0; ks < 8; ++ks) {
            const int cb = ks * 32 + quad * 8;
            bf16x8 af  = *(const bf16x8*)&Pw[w][l15][cb ^ sw];
            bf16x8 bf0 = *(const bf16x8*)&Vt[l15][cb ^ sw];
            bf16x8 bf1 = *(const bf16x8*)&Vt[16 + l15][cb ^ sw];
            O0 = __builtin_amdgcn_mfma_f32_16x16x32_bf16(af, bf0, O0, 0, 0, 0);
            O1 = __builtin_amdgcn_mfma_f32_16x16x32_bf16(af, bf1, O1, 0, 0, 0);
        }

        // epilogue: rows quad*4+r match this thread's inv[r]
#pragma unroll
        for (int r = 0; r < 4; ++r) {
            const int token = rb * 16 + quad * 4 + r;
            short* dst = out16 + ((size_t)(b * N_TOK + token)) * DIM_C + h * HD;
            dst[l15]      = f2bf_fast(O0[r] * inv[r]);
            dst[16 + l15] = f2bf_fast(O1[r] * inv[r]);
        }
    }
}

// ---------------------------------------------------------------------------
// Launch
// ---------------------------------------------------------------------------
extern "C" void kernel_launch(void* const* d_in, const int* in_sizes, int n_in,
                              void* d_out, int out_size, void* d_ws, size_t ws_size,
                              hipStream_t stream)
{
    const float* x      = (const float*)d_in[0];   // (256,256,192)
    const float* scale  = (const float*)d_in[1];   // (1,2)
    const float* mask   = (const float*)d_in[2];   // (64,256,256)
    const float* qkv_w  = (const float*)d_in[3];   // (576,192)
    const float* qkv_b  = (const float*)d_in[4];   // (576,)
    const float* cpb_w1 = (const float*)d_in[5];   // (512,4)
    const float* cpb_b1 = (const float*)d_in[6];   // (512,)
    const float* cpb_w2 = (const float*)d_in[7];   // (6,512)
    const float* cpb_b2 = (const float*)d_in[8];   // (6,)
    const float* proj_w = (const float*)d_in[9];   // (192,192)
    const float* proj_b = (const float*)d_in[10];  // (192,)
    float* out = (float*)d_out;                    // (256,256,192) fp32

    const size_t per = (size_t)B_WIN * NHEADS * N_TOK * HD;  // 12,582,912
    short* wss     = (short*)d_ws;
    short* qb      = wss;
    short* kb      = qb + per;
    short* vb      = kb + per;
    short* ao      = vb + per;
    short* x16     = ao + per;                    // UNUSED now (kept for layout)
    short* bias_p  = x16 + per;                   // 6*65536  =   393,216
    short* mask_p  = bias_p + 393216;             // 64*65536 = 4,194,304
    short* qkvw16  = mask_p + 4194304;            // 110,592
    short* projw16 = qkvw16 + 110592;             // 36,864
    float* table   = (float*)(projw16 + 36864);   // 961*6 fp32

    cpb_table_kernel<<<961, 512, 0, stream>>>(scale, cpb_w1, cpb_b1, cpb_w2, cpb_b2, table);

    bias_perm_kernel<<<(NHEADS * 8192) / 256, 256, 0, stream>>>(table, bias_p);
    mask_perm_kernel<<<(64 * 8192) / 256, 256, 0, stream>>>(mask, mask_p);

    f32_to_bf16_kernel<<<(110592 / 4 + 255) / 256, 256, 0, stream>>>(qkv_w, qkvw16, 110592 / 4);
    f32_to_bf16_kernel<<<(36864 / 4 + 255) / 256, 256, 0, stream>>>(proj_w, projw16, 36864 / 4);

    qkv_gemm_kernel<<<3072, 256, 0, stream>>>(x, qkvw16, qkv_b, qb, kb, vb);

    attn_mfma_kernel<<<NHEADS * B_WIN, 256, 0, stream>>>(qb, kb, vb, bias_p, mask_p, ao);

    proj_gemm_kernel<<<1024, 256, 0, stream>>>(ao, projw16, proj_b, out);
}

// Round 4
// 347.783 us; speedup vs baseline: 1.0564x; 1.0564x over previous
//
#include <hip/hip_runtime.h>
#include <math.h>

// Problem constants:
//   WH=WW=16, N=256 tokens/window, H=6 heads, DIM=192, hd=32
//   B_=256 windows, nW=64 mask windows, qk_scale = 32^-0.5
#define N_TOK 256
#define NHEADS 6
#define DIM_C 192
#define HD 32
#define B_WIN 256

typedef short bf16x8 __attribute__((ext_vector_type(8)));   // 8 bf16 in 4 VGPRs
typedef float f32x4 __attribute__((ext_vector_type(4)));

__device__ inline short f2bf(float f) {          // RNE
    unsigned u = __float_as_uint(f);
    u = (u + 0x7fffu + ((u >> 16) & 1u)) >> 16;
    return (short)u;
}
__device__ inline short f2bf_fast(float f) {     // round-half-up (0.5 ulp)
    return (short)((__float_as_uint(f) + 0x8000u) >> 16);
}
__device__ inline float bf2f(short s) {
    return __uint_as_float(((unsigned)(unsigned short)s) << 16);
}
// packed RNE f32x2 -> bf16x2 (one VALU op; same rounding as f2bf)
__device__ inline unsigned cvt_pk_bf16(float lo, float hi) {
    unsigned r;
    asm("v_cvt_pk_bf16_f32 %0, %1, %2" : "=v"(r) : "v"(lo), "v"(hi));
    return r;
}

// ---------------------------------------------------------------------------
// Kernel 1: CPB MLP -> table (961 x 6) fp32
// ---------------------------------------------------------------------------
__global__ __launch_bounds__(512) void cpb_table_kernel(
    const float* __restrict__ scale, const float* __restrict__ w1,
    const float* __restrict__ b1, const float* __restrict__ w2,
    const float* __restrict__ b2, float* __restrict__ table)
{
    __shared__ float red[512];
    const int e = blockIdx.x;            // 0..960
    const int i = e / 31, j = e % 31;
    const float t0 = ((float)(i - 15)) * (8.0f / 15.0f);
    const float t1 = ((float)(j - 15)) * (8.0f / 15.0f);
    const float s0 = scale[0], s1 = scale[1];
    const int t = threadIdx.x;
    const float* w = w1 + t * 4;
    float h = w[0] * t0 + w[1] * t1 + w[2] * s0 + w[3] * s1 + b1[t];
    h = fmaxf(h, 0.0f);
    for (int head = 0; head < NHEADS; ++head) {
        red[t] = h * w2[head * 512 + t];
        __syncthreads();
        for (int s = 256; s > 0; s >>= 1) {
            if (t < s) red[t] += red[t + s];
            __syncthreads();
        }
        if (t == 0) table[e * NHEADS + head] = red[0] + b2[head];
        __syncthreads();
    }
}

// ---------------------------------------------------------------------------
// MFMA-C-layout permuted index helper. Slab layout (65536 bf16):
//   offset = ((rb*8 + g)*64 + lane)*8 + (nt&1)*4 + r
//   where row = rb*16 + (lane>>4)*4 + r,  col = nt*16 + (lane&15),  nt = 2g+(j>>2)
// Thread j in [0,8): nt = 2g + (j>>2), r = j&3.
// ---------------------------------------------------------------------------

// Kernel 2a: bias -> permuted bf16 (6 slabs). One thread per 8 outputs.
__global__ __launch_bounds__(256) void bias_perm_kernel(
    const float* __restrict__ table, short* __restrict__ bias_p)
{
    const int idx8 = blockIdx.x * 256 + threadIdx.x;   // < 6*8192
    const int h = idx8 >> 13;
    const int rem = idx8 & 8191;
    const int rb = rem >> 9;
    const int g = (rem >> 6) & 7;
    const int lane = rem & 63;
    const int quad = lane >> 4, l15 = lane & 15;
    bf16x8 o;
#pragma unroll
    for (int j = 0; j < 8; ++j) {
        const int nt = g * 2 + (j >> 2), r = j & 3;
        const int row = rb * 16 + quad * 4 + r;
        const int col = nt * 16 + l15;
        const int rel0 = (row >> 4) - (col >> 4) + 15;
        const int rel1 = (row & 15) - (col & 15) + 15;
        o[j] = f2bf(table[(rel0 * 31 + rel1) * NHEADS + h]);
    }
    ((bf16x8*)bias_p)[idx8] = o;
}

// Kernel 2b: mask -> permuted bf16 (64 slabs).
__global__ __launch_bounds__(256) void mask_perm_kernel(
    const float* __restrict__ mask, short* __restrict__ mask_p)
{
    const int idx8 = blockIdx.x * 256 + threadIdx.x;   // < 64*8192
    const int bw = idx8 >> 13;
    const int rem = idx8 & 8191;
    const int rb = rem >> 9;
    const int g = (rem >> 6) & 7;
    const int lane = rem & 63;
    const int quad = lane >> 4, l15 = lane & 15;
    const float* ms = mask + ((size_t)bw << 16);
    bf16x8 o;
#pragma unroll
    for (int j = 0; j < 8; ++j) {
        const int nt = g * 2 + (j >> 2), r = j & 3;
        const int row = rb * 16 + quad * 4 + r;
        const int col = nt * 16 + l15;
        o[j] = f2bf(ms[row * 256 + col]);
    }
    ((bf16x8*)mask_p)[idx8] = o;
}

// ---------------------------------------------------------------------------
// Kernel 2c: generic fp32 -> bf16 (n4 = count/4)  [weights only]
// ---------------------------------------------------------------------------
__global__ __launch_bounds__(256) void f32_to_bf16_kernel(
    const float* __restrict__ in, short* __restrict__ out, int n4)
{
    const int i = blockIdx.x * 256 + threadIdx.x;
    if (i < n4) {
        float4 v = ((const float4*)in)[i];
        short4 s;
        s.x = f2bf(v.x); s.y = f2bf(v.y); s.z = f2bf(v.z); s.w = f2bf(v.w);
        ((short4*)out)[i] = s;
    }
}

// ---------------------------------------------------------------------------
// Kernel 3: QKV GEMM, no LDS (R1 structure — proven fastest). Per block:
// 128 rows (4 waves x 32) x 64 cols, K=192 fully unrolled, A and W fragments
// loaded directly from global. New vs R1:
//  - A is read as fp32 and converted in-register via v_cvt_pk_bf16_f32
//    (RNE, 1 op / 2 elems) -> the separate x->bf16 pass is gone.
//  - XCD-chunked 1D grid: the 9 blocks sharing one 128-row A panel run
//    consecutively on the SAME XCD -> panel hits L2 after the first read
//    (R1's FETCH showed ~4x A amplification from cross-XCD scatter).
// R2/R3 post-mortem: LDS staging + barrier + bank conflicts made latency
// hiding WORSE (127-130 us vs 90 us no-LDS). This keeps the no-LDS form.
// ---------------------------------------------------------------------------
__global__ __launch_bounds__(256) void qkv_gemm_kernel(
    const float* __restrict__ x, const short* __restrict__ w16,
    const float* __restrict__ qkv_b,
    short* __restrict__ qb, short* __restrict__ kb, short* __restrict__ vb)
{
    const int t = threadIdx.x;
    const int lane = t & 63;
    const int w = t >> 6;
    const int l15 = lane & 15, quad = lane >> 4;

    // XCD-chunked decode: 4608 blocks = 8 xcd * 64 panel-groups * 9 n-tiles
    const int l = blockIdx.x;
    const int xcd = l & 7;
    const int s = l >> 3;                // 0..575
    const int nt = s % 9;                // n-tile 0..8
    const int panel = xcd + 8 * (s / 9); // 0..511
    const int m0 = panel * 128 + w * 32;
    const int n0 = nt * 64;

    f32x4 acc[2][4] = {};
#pragma unroll
    for (int ks = 0; ks < 6; ++ks) {
        bf16x8 af[2];
#pragma unroll
        for (int mt = 0; mt < 2; ++mt) {
            const float* ap = x + (size_t)(m0 + mt * 16 + l15) * DIM_C + ks * 32 + quad * 8;
            const float4 v0 = *(const float4*)ap;
            const float4 v1 = *(const float4*)(ap + 4);
            union { bf16x8 v; unsigned u[4]; } cv;
            cv.u[0] = cvt_pk_bf16(v0.x, v0.y);
            cv.u[1] = cvt_pk_bf16(v0.z, v0.w);
            cv.u[2] = cvt_pk_bf16(v1.x, v1.y);
            cv.u[3] = cvt_pk_bf16(v1.z, v1.w);
            af[mt] = cv.v;
        }
        bf16x8 bfr[4];
#pragma unroll
        for (int c4 = 0; c4 < 4; ++c4)
            bfr[c4] = *(const bf16x8*)(w16 + (size_t)(n0 + c4 * 16 + l15) * DIM_C + ks * 32 + quad * 8);
#pragma unroll
        for (int mt = 0; mt < 2; ++mt)
#pragma unroll
            for (int c4 = 0; c4 < 4; ++c4)
                acc[mt][c4] = __builtin_amdgcn_mfma_f32_16x16x32_bf16(af[mt], bfr[c4], acc[mt][c4], 0, 0, 0);
    }

    const int which = nt / 3;                   // 0=q,1=k,2=v (constant per block)
    short* outp = (which == 0) ? qb : (which == 1) ? kb : vb;
    const float qscale = (which == 0) ? 0.17677669529663689f : 1.0f;
#pragma unroll
    for (int mt = 0; mt < 2; ++mt) {
#pragma unroll
        for (int r = 0; r < 4; ++r) {
            const int m = m0 + mt * 16 + quad * 4 + r;
            const int b = m >> 8, tok = m & 255;
#pragma unroll
            for (int c4 = 0; c4 < 4; ++c4) {
                const int c = n0 + c4 * 16 + l15;
                const int rem = c - which * DIM_C;
                const int h = rem >> 5, d = rem & 31;
                const float val = (acc[mt][c4][r] + qkv_b[c]) * qscale;
                outp[((size_t)((b * NHEADS + h) * N_TOK + tok)) * HD + d] = f2bf(val);
            }
        }
    }
}

// ---------------------------------------------------------------------------
// Kernel 5: proj GEMM, no LDS (R1 structure) + XCD-chunked grid.
// 1536 blocks = 8 xcd * 64 panel-groups * 3 n-tiles.
// ---------------------------------------------------------------------------
__global__ __launch_bounds__(256) void proj_gemm_kernel(
    const short* __restrict__ A16, const short* __restrict__ w16,
    const float* __restrict__ proj_b, float* __restrict__ out)
{
    const int t = threadIdx.x;
    const int lane = t & 63;
    const int w = t >> 6;
    const int l15 = lane & 15, quad = lane >> 4;

    const int l = blockIdx.x;
    const int xcd = l & 7;
    const int s = l >> 3;                // 0..191
    const int nt = s % 3;
    const int panel = xcd + 8 * (s / 3); // 0..511
    const int m0 = panel * 128 + w * 32;
    const int n0 = nt * 64;

    f32x4 acc[2][4] = {};
#pragma unroll
    for (int ks = 0; ks < 6; ++ks) {
        bf16x8 af[2];
#pragma unroll
        for (int mt = 0; mt < 2; ++mt)
            af[mt] = *(const bf16x8*)(A16 + (size_t)(m0 + mt * 16 + l15) * DIM_C + ks * 32 + quad * 8);
        bf16x8 bfr[4];
#pragma unroll
        for (int c4 = 0; c4 < 4; ++c4)
            bfr[c4] = *(const bf16x8*)(w16 + (size_t)(n0 + c4 * 16 + l15) * DIM_C + ks * 32 + quad * 8);
#pragma unroll
        for (int mt = 0; mt < 2; ++mt)
#pragma unroll
            for (int c4 = 0; c4 < 4; ++c4)
                acc[mt][c4] = __builtin_amdgcn_mfma_f32_16x16x32_bf16(af[mt], bfr[c4], acc[mt][c4], 0, 0, 0);
    }

#pragma unroll
    for (int mt = 0; mt < 2; ++mt) {
#pragma unroll
        for (int r = 0; r < 4; ++r) {
            const int m = m0 + mt * 16 + quad * 4 + r;
#pragma unroll
            for (int c4 = 0; c4 < 4; ++c4) {
                const int c = n0 + c4 * 16 + l15;
                out[(size_t)m * DIM_C + c] = acc[mt][c4][r] + proj_b[c];
            }
        }
    }
}

// ---------------------------------------------------------------------------
// Kernel 4: MFMA attention per (b,h), wave-owns-rows structure.
//  - 1D grid + XCD-aware swizzle: all 24 blocks sharing a mask slab (bw)
//    run consecutively on one XCD.
//  - K fragments hoisted into registers once per block (chunk-invariant).
//  - bias+mask fed as the MFMA C operand (pre-permuted tables).
// ---------------------------------------------------------------------------
#define PS_LD 264   // shorts; 528 B/row (16B aligned)

__global__ __launch_bounds__(256, 3) void attn_mfma_kernel(
    const short* __restrict__ q, const short* __restrict__ k,
    const short* __restrict__ v, const short* __restrict__ bias_p,
    const short* __restrict__ mask_p, short* __restrict__ out16)
{
    __shared__ __align__(16) short Vt[32][PS_LD];      // V^T, 16.9 KB
    __shared__ __align__(16) short Pw[4][16][PS_LD];   // per-wave P, 33.8 KB

    // XCD-aware swizzle (bijective on 1536 = 8 xcd * 8 bw-groups * 24 jobs)
    const int l = blockIdx.x;            // 0..1535
    const int s = l >> 3;                // 0..191
    const int bw = (l & 7) + 8 * (s / 24);
    const int j = s % 24;
    const int h = j % 6;                 // 0..5
    const int b = (j / 6) * 64 + bw;     // 0..255

    const int t = threadIdx.x;
    const int lane = t & 63;
    const int w = t >> 6;
    const int l15 = lane & 15;
    const int quad = lane >> 4;
    const size_t slab = ((size_t)(b * NHEADS + h)) * (N_TOK * HD);

    // stage V^T (thread t -> token t), swizzled columns
    {
        const bf16x8* vrow = (const bf16x8*)(v + slab + (size_t)t * HD);
#pragma unroll
        for (int u = 0; u < 4; ++u) {
            bf16x8 vv = vrow[u];
#pragma unroll
            for (int jj = 0; jj < 8; ++jj) {
                const int d = u * 8 + jj;
                Vt[d][t ^ (((d >> 3) & 1) * 16)] = vv[jj];
            }
        }
    }

    // K fragments: chunk-invariant, load once (16 x bf16x8 = 64 VGPRs)
    bf16x8 kfr[16];
#pragma unroll
    for (int nt = 0; nt < 16; ++nt)
        kfr[nt] = *(const bf16x8*)(k + slab + (size_t)(nt * 16 + l15) * HD + quad * 8);

    __syncthreads();   // Vt ready (only barrier in the kernel body)

    const short* bslab = bias_p + h * 65536;
    const short* mslab = mask_p + bw * 65536;

    for (int chunk = 0; chunk < 4; ++chunk) {
        const int rb = chunk * 4 + w;    // row block 0..15

        // Q fragment: rows rb*16 + l15, k = quad*8..+7
        const bf16x8 qf = *(const bf16x8*)(q + slab + (size_t)(rb * 16 + l15) * HD + quad * 8);

        // QK^T with bias+mask injected as C:
        // C-layout: row = rb*16+quad*4+r, col = nt*16+l15
        f32x4 S[16];
#pragma unroll
        for (int half = 0; half < 2; ++half) {
            bf16x8 bb[4], mm[4];
#pragma unroll
            for (int gg = 0; gg < 4; ++gg) {
                const int g = half * 4 + gg;
                const int off = ((rb * 8 + g) * 64 + lane) * 8;
                bb[gg] = *(const bf16x8*)(bslab + off);
                mm[gg] = *(const bf16x8*)(mslab + off);
            }
#pragma unroll
            for (int gg = 0; gg < 4; ++gg) {
                const int g = half * 4 + gg;
                f32x4 c0, c1;
#pragma unroll
                for (int r = 0; r < 4; ++r) {
                    c0[r] = bf2f(bb[gg][r])     + bf2f(mm[gg][r]);
                    c1[r] = bf2f(bb[gg][4 + r]) + bf2f(mm[gg][4 + r]);
                }
                S[g * 2]     = __builtin_amdgcn_mfma_f32_16x16x32_bf16(qf, kfr[g * 2],     c0, 0, 0, 0);
                S[g * 2 + 1] = __builtin_amdgcn_mfma_f32_16x16x32_bf16(qf, kfr[g * 2 + 1], c1, 0, 0, 0);
            }
        }

        // row max over register tiles, then across l15 lanes
        float mx[4] = {-1e30f, -1e30f, -1e30f, -1e30f};
#pragma unroll
        for (int nt = 0; nt < 16; ++nt)
#pragma unroll
            for (int r = 0; r < 4; ++r)
                mx[r] = fmaxf(mx[r], S[nt][r]);
#pragma unroll
        for (int r = 0; r < 4; ++r) {
            mx[r] = fmaxf(mx[r], __shfl_xor(mx[r], 1));
            mx[r] = fmaxf(mx[r], __shfl_xor(mx[r], 2));
            mx[r] = fmaxf(mx[r], __shfl_xor(mx[r], 4));
            mx[r] = fmaxf(mx[r], __shfl_xor(mx[r], 8));
        }

        // exp + row sum + P -> per-wave LDS (swizzled)
        float sm[4] = {0.f, 0.f, 0.f, 0.f};
#pragma unroll
        for (int nt = 0; nt < 16; ++nt) {
#pragma unroll
            for (int r = 0; r < 4; ++r) {
                const float p = __expf(S[nt][r] - mx[r]);
                sm[r] += p;
                const int lr = quad * 4 + r;
                Pw[w][lr][(nt * 16 + l15) ^ (((lr >> 3) & 1) * 16)] = f2bf_fast(p);
            }
        }
        float inv[4];
#pragma unroll
        for (int r = 0; r < 4; ++r) {
            sm[r] += __shfl_xor(sm[r], 1);
            sm[r] += __shfl_xor(sm[r], 2);
            sm[r] += __shfl_xor(sm[r], 4);
            sm[r] += __shfl_xor(sm[r], 8);
            inv[r] = __builtin_amdgcn_rcpf(sm[r]);
        }

        // wave-local LDS: drain writes before fragment reads
        __asm__ volatile("s_waitcnt lgkmcnt(0)" ::: "memory");

        // PV: O (16 rows x 32 d), A-frags from own Pw, B-frags from Vt
        f32x4 O0 = {0.f, 0.f, 0.f, 0.f};
        f32x4 O1 = {0.f, 0.f, 0.f, 0.f};
        const int sw = ((l15 >> 3) & 1) * 16;
#pragma unroll
        for (int ks = 0; ks < 8; ++ks) {
            const int cb = ks * 32 + quad * 8;
            bf16x8 af  = *(const bf16x8*)&Pw[w][l15][cb ^ sw];
            bf16x8 bf0 = *(const bf16x8*)&Vt[l15][cb ^ sw];
            bf16x8 bf1 = *(const bf16x8*)&Vt[16 + l15][cb ^ sw];
            O0 = __builtin_amdgcn_mfma_f32_16x16x32_bf16(af, bf0, O0, 0, 0, 0);
            O1 = __builtin_amdgcn_mfma_f32_16x16x32_bf16(af, bf1, O1, 0, 0, 0);
        }

        // epilogue: rows quad*4+r match this thread's inv[r]
#pragma unroll
        for (int r = 0; r < 4; ++r) {
            const int token = rb * 16 + quad * 4 + r;
            short* dst = out16 + ((size_t)(b * N_TOK + token)) * DIM_C + h * HD;
            dst[l15]      = f2bf_fast(O0[r] * inv[r]);
            dst[16 + l15] = f2bf_fast(O1[r] * inv[r]);
        }
    }
}

// ---------------------------------------------------------------------------
// Launch
// ---------------------------------------------------------------------------
extern "C" void kernel_launch(void* const* d_in, const int* in_sizes, int n_in,
                              void* d_out, int out_size, void* d_ws, size_t ws_size,
                              hipStream_t stream)
{
    const float* x      = (const float*)d_in[0];   // (256,256,192)
    const float* scale  = (const float*)d_in[1];   // (1,2)
    const float* mask   = (const float*)d_in[2];   // (64,256,256)
    const float* qkv_w  = (const float*)d_in[3];   // (576,192)
    const float* qkv_b  = (const float*)d_in[4];   // (576,)
    const float* cpb_w1 = (const float*)d_in[5];   // (512,4)
    const float* cpb_b1 = (const float*)d_in[6];   // (512,)
    const float* cpb_w2 = (const float*)d_in[7];   // (6,512)
    const float* cpb_b2 = (const float*)d_in[8];   // (6,)
    const float* proj_w = (const float*)d_in[9];   // (192,192)
    const float* proj_b = (const float*)d_in[10];  // (192,)
    float* out = (float*)d_out;                    // (256,256,192) fp32

    const size_t per = (size_t)B_WIN * NHEADS * N_TOK * HD;  // 12,582,912
    short* wss     = (short*)d_ws;
    short* qb      = wss;
    short* kb      = qb + per;
    short* vb      = kb + per;
    short* ao      = vb + per;
    short* x16     = ao + per;                    // UNUSED now (kept for layout)
    short* bias_p  = x16 + per;                   // 6*65536  =   393,216
    short* mask_p  = bias_p + 393216;             // 64*65536 = 4,194,304
    short* qkvw16  = mask_p + 4194304;            // 110,592
    short* projw16 = qkvw16 + 110592;             // 36,864
    float* table   = (float*)(projw16 + 36864);   // 961*6 fp32

    cpb_table_kernel<<<961, 512, 0, stream>>>(scale, cpb_w1, cpb_b1, cpb_w2, cpb_b2, table);

    bias_perm_kernel<<<(NHEADS * 8192) / 256, 256, 0, stream>>>(table, bias_p);
    mask_perm_kernel<<<(64 * 8192) / 256, 256, 0, stream>>>(mask, mask_p);

    f32_to_bf16_kernel<<<(110592 / 4 + 255) / 256, 256, 0, stream>>>(qkv_w, qkvw16, 110592 / 4);
    f32_to_bf16_kernel<<<(36864 / 4 + 255) / 256, 256, 0, stream>>>(proj_w, projw16, 36864 / 4);

    qkv_gemm_kernel<<<4608, 256, 0, stream>>>(x, qkvw16, qkv_b, qb, kb, vb);

    attn_mfma_kernel<<<NHEADS * B_WIN, 256, 0, stream>>>(qb, kb, vb, bias_p, mask_p, ao);

    proj_gemm_kernel<<<1536, 256, 0, stream>>>(ao, projw16, proj_b, out);
}

// Round 5
// 324.110 us; speedup vs baseline: 1.1336x; 1.0730x over previous
//
#include <hip/hip_runtime.h>
#include <math.h>

// Problem constants:
//   WH=WW=16, N=256 tokens/window, H=6 heads, DIM=192, hd=32
//   B_=256 windows, nW=64 mask windows, qk_scale = 32^-0.5
#define N_TOK 256
#define NHEADS 6
#define DIM_C 192
#define HD 32
#define B_WIN 256

typedef short bf16x8 __attribute__((ext_vector_type(8)));   // 8 bf16 in 4 VGPRs
typedef float f32x4 __attribute__((ext_vector_type(4)));

__device__ inline short f2bf(float f) {          // RNE
    unsigned u = __float_as_uint(f);
    u = (u + 0x7fffu + ((u >> 16) & 1u)) >> 16;
    return (short)u;
}
__device__ inline short f2bf_fast(float f) {     // round-half-up (0.5 ulp)
    return (short)((__float_as_uint(f) + 0x8000u) >> 16);
}
__device__ inline float bf2f(short s) {
    return __uint_as_float(((unsigned)(unsigned short)s) << 16);
}

// ---------------------------------------------------------------------------
// Kernel 1: CPB MLP -> table (961 x 6) fp32
// ---------------------------------------------------------------------------
__global__ __launch_bounds__(512) void cpb_table_kernel(
    const float* __restrict__ scale, const float* __restrict__ w1,
    const float* __restrict__ b1, const float* __restrict__ w2,
    const float* __restrict__ b2, float* __restrict__ table)
{
    __shared__ float red[512];
    const int e = blockIdx.x;            // 0..960
    const int i = e / 31, j = e % 31;
    const float t0 = ((float)(i - 15)) * (8.0f / 15.0f);
    const float t1 = ((float)(j - 15)) * (8.0f / 15.0f);
    const float s0 = scale[0], s1 = scale[1];
    const int t = threadIdx.x;
    const float* w = w1 + t * 4;
    float h = w[0] * t0 + w[1] * t1 + w[2] * s0 + w[3] * s1 + b1[t];
    h = fmaxf(h, 0.0f);
    for (int head = 0; head < NHEADS; ++head) {
        red[t] = h * w2[head * 512 + t];
        __syncthreads();
        for (int s = 256; s > 0; s >>= 1) {
            if (t < s) red[t] += red[t + s];
            __syncthreads();
        }
        if (t == 0) table[e * NHEADS + head] = red[0] + b2[head];
        __syncthreads();
    }
}

// ---------------------------------------------------------------------------
// MFMA-C-layout permuted index helper. Slab layout (65536 bf16):
//   offset = ((rb*8 + g)*64 + lane)*8 + (nt&1)*4 + r
//   where row = rb*16 + (lane>>4)*4 + r,  col = nt*16 + (lane&15),  nt = 2g+(j>>2)
// Thread j in [0,8): nt = 2g + (j>>2), r = j&3.
// ---------------------------------------------------------------------------

// Kernel 2a: bias -> permuted bf16 (6 slabs). One thread per 8 outputs.
__global__ __launch_bounds__(256) void bias_perm_kernel(
    const float* __restrict__ table, short* __restrict__ bias_p)
{
    const int idx8 = blockIdx.x * 256 + threadIdx.x;   // < 6*8192
    const int h = idx8 >> 13;
    const int rem = idx8 & 8191;
    const int rb = rem >> 9;
    const int g = (rem >> 6) & 7;
    const int lane = rem & 63;
    const int quad = lane >> 4, l15 = lane & 15;
    bf16x8 o;
#pragma unroll
    for (int j = 0; j < 8; ++j) {
        const int nt = g * 2 + (j >> 2), r = j & 3;
        const int row = rb * 16 + quad * 4 + r;
        const int col = nt * 16 + l15;
        const int rel0 = (row >> 4) - (col >> 4) + 15;
        const int rel1 = (row & 15) - (col & 15) + 15;
        o[j] = f2bf(table[(rel0 * 31 + rel1) * NHEADS + h]);
    }
    ((bf16x8*)bias_p)[idx8] = o;
}

// Kernel 2b: mask -> permuted bf16 (64 slabs).
__global__ __launch_bounds__(256) void mask_perm_kernel(
    const float* __restrict__ mask, short* __restrict__ mask_p)
{
    const int idx8 = blockIdx.x * 256 + threadIdx.x;   // < 64*8192
    const int bw = idx8 >> 13;
    const int rem = idx8 & 8191;
    const int rb = rem >> 9;
    const int g = (rem >> 6) & 7;
    const int lane = rem & 63;
    const int quad = lane >> 4, l15 = lane & 15;
    const float* ms = mask + ((size_t)bw << 16);
    bf16x8 o;
#pragma unroll
    for (int j = 0; j < 8; ++j) {
        const int nt = g * 2 + (j >> 2), r = j & 3;
        const int row = rb * 16 + quad * 4 + r;
        const int col = nt * 16 + l15;
        o[j] = f2bf(ms[row * 256 + col]);
    }
    ((bf16x8*)mask_p)[idx8] = o;
}

// ---------------------------------------------------------------------------
// Kernel 2c: generic fp32 -> bf16 (n4 = count/4)
// ---------------------------------------------------------------------------
__global__ __launch_bounds__(256) void f32_to_bf16_kernel(
    const float* __restrict__ in, short* __restrict__ out, int n4)
{
    const int i = blockIdx.x * 256 + threadIdx.x;
    if (i < n4) {
        float4 v = ((const float4*)in)[i];
        short4 s;
        s.x = f2bf(v.x); s.y = f2bf(v.y); s.z = f2bf(v.z); s.w = f2bf(v.w);
        ((short4*)out)[i] = s;
    }
}

// ---------------------------------------------------------------------------
// Kernel 3: QKV GEMM, no LDS. R4 post-mortem: fp32 A doubled cache-side
// traffic (450 MB logical) and 52 VGPRs forced serial load->MFMA rounds.
// This round: bf16 A (x16 precomputed), 96-col blocks.
//   grid 3072 = 8 xcd * 64 panel-groups * 6 col-blocks
//   per wave: 32 rows x 96 cols, acc[2][6] (48 VGPR) -> compiler has room
//   to pipeline next-K W loads under MFMAs; per K-step 8 independent loads
//   + 12 MFMAs. Logical A: 6 passes x 25 MB = 150 MB, and per-XCD A slice
//   (64 panels x 49 KB = 3.1 MB) fits the 4 MB XCD L2 -> A L2-resident.
// ---------------------------------------------------------------------------
__global__ __launch_bounds__(256) void qkv_gemm_kernel(
    const short* __restrict__ x16, const short* __restrict__ w16,
    const float* __restrict__ qkv_b,
    short* __restrict__ qb, short* __restrict__ kb, short* __restrict__ vb)
{
    const int t = threadIdx.x;
    const int lane = t & 63;
    const int w = t >> 6;
    const int l15 = lane & 15, quad = lane >> 4;

    const int l = blockIdx.x;            // 0..3071
    const int xcd = l & 7;
    const int s = l >> 3;                // 0..383
    const int cb = s % 6;                // col-block 0..5 (96 cols each)
    const int panel = xcd + 8 * (s / 6); // 0..511
    const int m0 = panel * 128 + w * 32;
    const int n0 = cb * 96;

    f32x4 acc[2][6] = {};
#pragma unroll
    for (int ks = 0; ks < 6; ++ks) {
        bf16x8 af[2];
#pragma unroll
        for (int mt = 0; mt < 2; ++mt)
            af[mt] = *(const bf16x8*)(x16 + (size_t)(m0 + mt * 16 + l15) * DIM_C + ks * 32 + quad * 8);
        bf16x8 bfr[6];
#pragma unroll
        for (int c4 = 0; c4 < 6; ++c4)
            bfr[c4] = *(const bf16x8*)(w16 + (size_t)(n0 + c4 * 16 + l15) * DIM_C + ks * 32 + quad * 8);
#pragma unroll
        for (int mt = 0; mt < 2; ++mt)
#pragma unroll
            for (int c4 = 0; c4 < 6; ++c4)
                acc[mt][c4] = __builtin_amdgcn_mfma_f32_16x16x32_bf16(af[mt], bfr[c4], acc[mt][c4], 0, 0, 0);
    }

    const int which = cb >> 1;           // 0=q,1=k,2=v (constant per block)
    short* outp = (which == 0) ? qb : (which == 1) ? kb : vb;
    const float qscale = (which == 0) ? 0.17677669529663689f : 1.0f;
#pragma unroll
    for (int mt = 0; mt < 2; ++mt) {
#pragma unroll
        for (int r = 0; r < 4; ++r) {
            const int m = m0 + mt * 16 + quad * 4 + r;
            const int b = m >> 8, tok = m & 255;
#pragma unroll
            for (int c4 = 0; c4 < 6; ++c4) {
                const int rem = (cb & 1) * 96 + c4 * 16 + l15;   // 0..191
                const int h = rem >> 5, d = rem & 31;
                const float val = (acc[mt][c4][r] + qkv_b[which * DIM_C + rem]) * qscale;
                outp[((size_t)((b * NHEADS + h) * N_TOK + tok)) * HD + d] = f2bf(val);
            }
        }
    }
}

// ---------------------------------------------------------------------------
// Kernel 5: proj GEMM, no LDS, 96-col blocks, XCD-chunked.
//   grid 1024 = 8 xcd * 64 panel-groups * 2 col-blocks
// ---------------------------------------------------------------------------
__global__ __launch_bounds__(256) void proj_gemm_kernel(
    const short* __restrict__ A16, const short* __restrict__ w16,
    const float* __restrict__ proj_b, float* __restrict__ out)
{
    const int t = threadIdx.x;
    const int lane = t & 63;
    const int w = t >> 6;
    const int l15 = lane & 15, quad = lane >> 4;

    const int l = blockIdx.x;            // 0..1023
    const int xcd = l & 7;
    const int s = l >> 3;                // 0..127
    const int cb = s % 2;                // col-block 0..1 (96 cols each)
    const int panel = xcd + 8 * (s / 2); // 0..511
    const int m0 = panel * 128 + w * 32;
    const int n0 = cb * 96;

    f32x4 acc[2][6] = {};
#pragma unroll
    for (int ks = 0; ks < 6; ++ks) {
        bf16x8 af[2];
#pragma unroll
        for (int mt = 0; mt < 2; ++mt)
            af[mt] = *(const bf16x8*)(A16 + (size_t)(m0 + mt * 16 + l15) * DIM_C + ks * 32 + quad * 8);
        bf16x8 bfr[6];
#pragma unroll
        for (int c4 = 0; c4 < 6; ++c4)
            bfr[c4] = *(const bf16x8*)(w16 + (size_t)(n0 + c4 * 16 + l15) * DIM_C + ks * 32 + quad * 8);
#pragma unroll
        for (int mt = 0; mt < 2; ++mt)
#pragma unroll
            for (int c4 = 0; c4 < 6; ++c4)
                acc[mt][c4] = __builtin_amdgcn_mfma_f32_16x16x32_bf16(af[mt], bfr[c4], acc[mt][c4], 0, 0, 0);
    }

#pragma unroll
    for (int mt = 0; mt < 2; ++mt) {
#pragma unroll
        for (int r = 0; r < 4; ++r) {
            const int m = m0 + mt * 16 + quad * 4 + r;
#pragma unroll
            for (int c4 = 0; c4 < 6; ++c4) {
                const int c = n0 + c4 * 16 + l15;
                out[(size_t)m * DIM_C + c] = acc[mt][c4][r] + proj_b[c];
            }
        }
    }
}

// ---------------------------------------------------------------------------
// Kernel 4: MFMA attention per (b,h), wave-owns-rows structure.
//  - 1D grid + XCD-aware swizzle: all 24 blocks sharing a mask slab (bw)
//    run consecutively on one XCD.
//  - K fragments hoisted into registers once per block (chunk-invariant).
//  - bias+mask fed as the MFMA C operand (pre-permuted tables).
// ---------------------------------------------------------------------------
#define PS_LD 264   // shorts; 528 B/row (16B aligned)

__global__ __launch_bounds__(256, 3) void attn_mfma_kernel(
    const short* __restrict__ q, const short* __restrict__ k,
    const short* __restrict__ v, const short* __restrict__ bias_p,
    const short* __restrict__ mask_p, short* __restrict__ out16)
{
    __shared__ __align__(16) short Vt[32][PS_LD];      // V^T, 16.9 KB
    __shared__ __align__(16) short Pw[4][16][PS_LD];   // per-wave P, 33.8 KB

    // XCD-aware swizzle (bijective on 1536 = 8 xcd * 8 bw-groups * 24 jobs)
    const int l = blockIdx.x;            // 0..1535
    const int s = l >> 3;                // 0..191
    const int bw = (l & 7) + 8 * (s / 24);
    const int j = s % 24;
    const int h = j % 6;                 // 0..5
    const int b = (j / 6) * 64 + bw;     // 0..255

    const int t = threadIdx.x;
    const int lane = t & 63;
    const int w = t >> 6;
    const int l15 = lane & 15;
    const int quad = lane >> 4;
    const size_t slab = ((size_t)(b * NHEADS + h)) * (N_TOK * HD);

    // stage V^T (thread t -> token t), swizzled columns
    {
        const bf16x8* vrow = (const bf16x8*)(v + slab + (size_t)t * HD);
#pragma unroll
        for (int u = 0; u < 4; ++u) {
            bf16x8 vv = vrow[u];
#pragma unroll
            for (int jj = 0; jj < 8; ++jj) {
                const int d = u * 8 + jj;
                Vt[d][t ^ (((d >> 3) & 1) * 16)] = vv[jj];
            }
        }
    }

    // K fragments: chunk-invariant, load once (16 x bf16x8 = 64 VGPRs)
    bf16x8 kfr[16];
#pragma unroll
    for (int nt = 0; nt < 16; ++nt)
        kfr[nt] = *(const bf16x8*)(k + slab + (size_t)(nt * 16 + l15) * HD + quad * 8);

    __syncthreads();   // Vt ready (only barrier in the kernel body)

    const short* bslab = bias_p + h * 65536;
    const short* mslab = mask_p + bw * 65536;

    for (int chunk = 0; chunk < 4; ++chunk) {
        const int rb = chunk * 4 + w;    // row block 0..15

        // Q fragment: rows rb*16 + l15, k = quad*8..+7
        const bf16x8 qf = *(const bf16x8*)(q + slab + (size_t)(rb * 16 + l15) * HD + quad * 8);

        // QK^T with bias+mask injected as C:
        // C-layout: row = rb*16+quad*4+r, col = nt*16+l15
        f32x4 S[16];
#pragma unroll
        for (int half = 0; half < 2; ++half) {
            bf16x8 bb[4], mm[4];
#pragma unroll
            for (int gg = 0; gg < 4; ++gg) {
                const int g = half * 4 + gg;
                const int off = ((rb * 8 + g) * 64 + lane) * 8;
                bb[gg] = *(const bf16x8*)(bslab + off);
                mm[gg] = *(const bf16x8*)(mslab + off);
            }
#pragma unroll
            for (int gg = 0; gg < 4; ++gg) {
                const int g = half * 4 + gg;
                f32x4 c0, c1;
#pragma unroll
                for (int r = 0; r < 4; ++r) {
                    c0[r] = bf2f(bb[gg][r])     + bf2f(mm[gg][r]);
                    c1[r] = bf2f(bb[gg][4 + r]) + bf2f(mm[gg][4 + r]);
                }
                S[g * 2]     = __builtin_amdgcn_mfma_f32_16x16x32_bf16(qf, kfr[g * 2],     c0, 0, 0, 0);
                S[g * 2 + 1] = __builtin_amdgcn_mfma_f32_16x16x32_bf16(qf, kfr[g * 2 + 1], c1, 0, 0, 0);
            }
        }

        // row max over register tiles, then across l15 lanes
        float mx[4] = {-1e30f, -1e30f, -1e30f, -1e30f};
#pragma unroll
        for (int nt = 0; nt < 16; ++nt)
#pragma unroll
            for (int r = 0; r < 4; ++r)
                mx[r] = fmaxf(mx[r], S[nt][r]);
#pragma unroll
        for (int r = 0; r < 4; ++r) {
            mx[r] = fmaxf(mx[r], __shfl_xor(mx[r], 1));
            mx[r] = fmaxf(mx[r], __shfl_xor(mx[r], 2));
            mx[r] = fmaxf(mx[r], __shfl_xor(mx[r], 4));
            mx[r] = fmaxf(mx[r], __shfl_xor(mx[r], 8));
        }

        // exp + row sum + P -> per-wave LDS (swizzled)
        float sm[4] = {0.f, 0.f, 0.f, 0.f};
#pragma unroll
        for (int nt = 0; nt < 16; ++nt) {
#pragma unroll
            for (int r = 0; r < 4; ++r) {
                const float p = __expf(S[nt][r] - mx[r]);
                sm[r] += p;
                const int lr = quad * 4 + r;
                Pw[w][lr][(nt * 16 + l15) ^ (((lr >> 3) & 1) * 16)] = f2bf_fast(p);
            }
        }
        float inv[4];
#pragma unroll
        for (int r = 0; r < 4; ++r) {
            sm[r] += __shfl_xor(sm[r], 1);
            sm[r] += __shfl_xor(sm[r], 2);
            sm[r] += __shfl_xor(sm[r], 4);
            sm[r] += __shfl_xor(sm[r], 8);
            inv[r] = __builtin_amdgcn_rcpf(sm[r]);
        }

        // wave-local LDS: drain writes before fragment reads
        __asm__ volatile("s_waitcnt lgkmcnt(0)" ::: "memory");

        // PV: O (16 rows x 32 d), A-frags from own Pw, B-frags from Vt
        f32x4 O0 = {0.f, 0.f, 0.f, 0.f};
        f32x4 O1 = {0.f, 0.f, 0.f, 0.f};
        const int sw = ((l15 >> 3) & 1) * 16;
#pragma unroll
        for (int ks = 0; ks < 8; ++ks) {
            const int cb = ks * 32 + quad * 8;
            bf16x8 af  = *(const bf16x8*)&Pw[w][l15][cb ^ sw];
            bf16x8 bf0 = *(const bf16x8*)&Vt[l15][cb ^ sw];
            bf16x8 bf1 = *(const bf16x8*)&Vt[16 + l15][cb ^ sw];
            O0 = __builtin_amdgcn_mfma_f32_16x16x32_bf16(af, bf0, O0, 0, 0, 0);
            O1 = __builtin_amdgcn_mfma_f32_16x16x32_bf16(af, bf1, O1, 0, 0, 0);
        }

        // epilogue: rows quad*4+r match this thread's inv[r]
#pragma unroll
        for (int r = 0; r < 4; ++r) {
            const int token = rb * 16 + quad * 4 + r;
            short* dst = out16 + ((size_t)(b * N_TOK + token)) * DIM_C + h * HD;
            dst[l15]      = f2bf_fast(O0[r] * inv[r]);
            dst[16 + l15] = f2bf_fast(O1[r] * inv[r]);
        }
    }
}

// ---------------------------------------------------------------------------
// Launch
// ---------------------------------------------------------------------------
extern "C" void kernel_launch(void* const* d_in, const int* in_sizes, int n_in,
                              void* d_out, int out_size, void* d_ws, size_t ws_size,
                              hipStream_t stream)
{
    const float* x      = (const float*)d_in[0];   // (256,256,192)
    const float* scale  = (const float*)d_in[1];   // (1,2)
    const float* mask   = (const float*)d_in[2];   // (64,256,256)
    const float* qkv_w  = (const float*)d_in[3];   // (576,192)
    const float* qkv_b  = (const float*)d_in[4];   // (576,)
    const float* cpb_w1 = (const float*)d_in[5];   // (512,4)
    const float* cpb_b1 = (const float*)d_in[6];   // (512,)
    const float* cpb_w2 = (const float*)d_in[7];   // (6,512)
    const float* cpb_b2 = (const float*)d_in[8];   // (6,)
    const float* proj_w = (const float*)d_in[9];   // (192,192)
    const float* proj_b = (const float*)d_in[10];  // (192,)
    float* out = (float*)d_out;                    // (256,256,192) fp32

    const size_t per = (size_t)B_WIN * NHEADS * N_TOK * HD;  // 12,582,912
    short* wss     = (short*)d_ws;
    short* qb      = wss;
    short* kb      = qb + per;
    short* vb      = kb + per;
    short* ao      = vb + per;
    short* x16     = ao + per;                    // 12,582,912
    short* bias_p  = x16 + per;                   // 6*65536  =   393,216
    short* mask_p  = bias_p + 393216;             // 64*65536 = 4,194,304
    short* qkvw16  = mask_p + 4194304;            // 110,592
    short* projw16 = qkvw16 + 110592;             // 36,864
    float* table   = (float*)(projw16 + 36864);   // 961*6 fp32

    cpb_table_kernel<<<961, 512, 0, stream>>>(scale, cpb_w1, cpb_b1, cpb_w2, cpb_b2, table);

    bias_perm_kernel<<<(NHEADS * 8192) / 256, 256, 0, stream>>>(table, bias_p);
    mask_perm_kernel<<<(64 * 8192) / 256, 256, 0, stream>>>(mask, mask_p);

    f32_to_bf16_kernel<<<(int)((per / 4 + 255) / 256), 256, 0, stream>>>(x, x16, (int)(per / 4));
    f32_to_bf16_kernel<<<(110592 / 4 + 255) / 256, 256, 0, stream>>>(qkv_w, qkvw16, 110592 / 4);
    f32_to_bf16_kernel<<<(36864 / 4 + 255) / 256, 256, 0, stream>>>(proj_w, projw16, 36864 / 4);

    qkv_gemm_kernel<<<3072, 256, 0, stream>>>(x16, qkvw16, qkv_b, qb, kb, vb);

    attn_mfma_kernel<<<NHEADS * B_WIN, 256, 0, stream>>>(qb, kb, vb, bias_p, mask_p, ao);

    proj_gemm_kernel<<<1024, 256, 0, stream>>>(ao, projw16, proj_b, out);
}

// Round 6
// 318.432 us; speedup vs baseline: 1.1538x; 1.0178x over previous
//
#include <hip/hip_runtime.h>
#include <math.h>

// Problem constants:
//   WH=WW=16, N=256 tokens/window, H=6 heads, DIM=192, hd=32
//   B_=256 windows, nW=64 mask windows, qk_scale = 32^-0.5
#define N_TOK 256
#define NHEADS 6
#define DIM_C 192
#define HD 32
#define B_WIN 256

typedef short bf16x8 __attribute__((ext_vector_type(8)));   // 8 bf16 in 4 VGPRs
typedef float f32x4 __attribute__((ext_vector_type(4)));

__device__ inline short f2bf(float f) {          // RNE
    unsigned u = __float_as_uint(f);
    u = (u + 0x7fffu + ((u >> 16) & 1u)) >> 16;
    return (short)u;
}
__device__ inline short f2bf_fast(float f) {     // round-half-up (0.5 ulp)
    return (short)((__float_as_uint(f) + 0x8000u) >> 16);
}
__device__ inline float bf2f(short s) {
    return __uint_as_float(((unsigned)(unsigned short)s) << 16);
}

// ---------------------------------------------------------------------------
// Kernel 1: CPB MLP -> table (961 x 6) fp32
// ---------------------------------------------------------------------------
__global__ __launch_bounds__(512) void cpb_table_kernel(
    const float* __restrict__ scale, const float* __restrict__ w1,
    const float* __restrict__ b1, const float* __restrict__ w2,
    const float* __restrict__ b2, float* __restrict__ table)
{
    __shared__ float red[512];
    const int e = blockIdx.x;            // 0..960
    const int i = e / 31, j = e % 31;
    const float t0 = ((float)(i - 15)) * (8.0f / 15.0f);
    const float t1 = ((float)(j - 15)) * (8.0f / 15.0f);
    const float s0 = scale[0], s1 = scale[1];
    const int t = threadIdx.x;
    const float* w = w1 + t * 4;
    float h = w[0] * t0 + w[1] * t1 + w[2] * s0 + w[3] * s1 + b1[t];
    h = fmaxf(h, 0.0f);
    for (int head = 0; head < NHEADS; ++head) {
        red[t] = h * w2[head * 512 + t];
        __syncthreads();
        for (int s = 256; s > 0; s >>= 1) {
            if (t < s) red[t] += red[t + s];
            __syncthreads();
        }
        if (t == 0) table[e * NHEADS + head] = red[0] + b2[head];
        __syncthreads();
    }
}

// ---------------------------------------------------------------------------
// MFMA-C-layout permuted index helper. Slab layout (65536 bf16):
//   offset = ((rb*8 + g)*64 + lane)*8 + (nt&1)*4 + r
//   where row = rb*16 + (lane>>4)*4 + r,  col = nt*16 + (lane&15),  nt = 2g+(j>>2)
// Thread j in [0,8): nt = 2g + (j>>2), r = j&3.
// ---------------------------------------------------------------------------

// Kernel 2a: bias -> permuted bf16 (6 slabs). One thread per 8 outputs.
__global__ __launch_bounds__(256) void bias_perm_kernel(
    const float* __restrict__ table, short* __restrict__ bias_p)
{
    const int idx8 = blockIdx.x * 256 + threadIdx.x;   // < 6*8192
    const int h = idx8 >> 13;
    const int rem = idx8 & 8191;
    const int rb = rem >> 9;
    const int g = (rem >> 6) & 7;
    const int lane = rem & 63;
    const int quad = lane >> 4, l15 = lane & 15;
    bf16x8 o;
#pragma unroll
    for (int j = 0; j < 8; ++j) {
        const int nt = g * 2 + (j >> 2), r = j & 3;
        const int row = rb * 16 + quad * 4 + r;
        const int col = nt * 16 + l15;
        const int rel0 = (row >> 4) - (col >> 4) + 15;
        const int rel1 = (row & 15) - (col & 15) + 15;
        o[j] = f2bf(table[(rel0 * 31 + rel1) * NHEADS + h]);
    }
    ((bf16x8*)bias_p)[idx8] = o;
}

// Kernel 2b: mask -> permuted bf16 (64 slabs).
__global__ __launch_bounds__(256) void mask_perm_kernel(
    const float* __restrict__ mask, short* __restrict__ mask_p)
{
    const int idx8 = blockIdx.x * 256 + threadIdx.x;   // < 64*8192
    const int bw = idx8 >> 13;
    const int rem = idx8 & 8191;
    const int rb = rem >> 9;
    const int g = (rem >> 6) & 7;
    const int lane = rem & 63;
    const int quad = lane >> 4, l15 = lane & 15;
    const float* ms = mask + ((size_t)bw << 16);
    bf16x8 o;
#pragma unroll
    for (int j = 0; j < 8; ++j) {
        const int nt = g * 2 + (j >> 2), r = j & 3;
        const int row = rb * 16 + quad * 4 + r;
        const int col = nt * 16 + l15;
        o[j] = f2bf(ms[row * 256 + col]);
    }
    ((bf16x8*)mask_p)[idx8] = o;
}

// ---------------------------------------------------------------------------
// Kernel 2c: generic fp32 -> bf16 (n4 = count/4)
// ---------------------------------------------------------------------------
__global__ __launch_bounds__(256) void f32_to_bf16_kernel(
    const float* __restrict__ in, short* __restrict__ out, int n4)
{
    const int i = blockIdx.x * 256 + threadIdx.x;
    if (i < n4) {
        float4 v = ((const float4*)in)[i];
        short4 s;
        s.x = f2bf(v.x); s.y = f2bf(v.y); s.z = f2bf(v.z); s.w = f2bf(v.w);
        ((short4*)out)[i] = s;
    }
}

// ---------------------------------------------------------------------------
// Kernel 3: QKV GEMM, no LDS, deep-ILP version. R5 post-mortem: VGPR=64
// forced one K-step of operands in flight -> 6 serial memory-latency rounds
// per wave (~4-5K cy) that ~3 co-resident blocks can't hide. This round:
//  - ALL 12 A fragments preloaded up-front (independent, chunk-invariant)
//  - W fragments double-buffered: W[ks+1] loads issue before ks's 12 MFMAs
//  - VGPR rises one occupancy tier (~160-190); chain/block drops ~3x.
// Grid 3072 = 8 xcd * 64 panel-groups * 6 col-blocks (96 cols each).
// ---------------------------------------------------------------------------
__global__ __launch_bounds__(256) void qkv_gemm_kernel(
    const short* __restrict__ x16, const short* __restrict__ w16,
    const float* __restrict__ qkv_b,
    short* __restrict__ qb, short* __restrict__ kb, short* __restrict__ vb)
{
    const int t = threadIdx.x;
    const int lane = t & 63;
    const int w = t >> 6;
    const int l15 = lane & 15, quad = lane >> 4;

    const int l = blockIdx.x;            // 0..3071
    const int xcd = l & 7;
    const int s = l >> 3;                // 0..383
    const int cb = s % 6;                // col-block 0..5 (96 cols each)
    const int panel = xcd + 8 * (s / 6); // 0..511
    const int m0 = panel * 128 + w * 32;
    const int n0 = cb * 96;

    // preload ALL A fragments: af[mt][ks] (12 x b128 = 48 VGPR), independent
    bf16x8 af[2][6];
#pragma unroll
    for (int mt = 0; mt < 2; ++mt)
#pragma unroll
        for (int ks = 0; ks < 6; ++ks)
            af[mt][ks] = *(const bf16x8*)(x16 + (size_t)(m0 + mt * 16 + l15) * DIM_C + ks * 32 + quad * 8);

    // W double buffer: prime ks=0
    bf16x8 wb[2][6];
#pragma unroll
    for (int c4 = 0; c4 < 6; ++c4)
        wb[0][c4] = *(const bf16x8*)(w16 + (size_t)(n0 + c4 * 16 + l15) * DIM_C + quad * 8);

    f32x4 acc[2][6] = {};
#pragma unroll
    for (int ks = 0; ks < 6; ++ks) {
        if (ks < 5) {
#pragma unroll
            for (int c4 = 0; c4 < 6; ++c4)
                wb[(ks + 1) & 1][c4] = *(const bf16x8*)(w16 + (size_t)(n0 + c4 * 16 + l15) * DIM_C + (ks + 1) * 32 + quad * 8);
        }
#pragma unroll
        for (int mt = 0; mt < 2; ++mt)
#pragma unroll
            for (int c4 = 0; c4 < 6; ++c4)
                acc[mt][c4] = __builtin_amdgcn_mfma_f32_16x16x32_bf16(af[mt][ks], wb[ks & 1][c4], acc[mt][c4], 0, 0, 0);
    }

    const int which = cb >> 1;           // 0=q,1=k,2=v (constant per block)
    short* outp = (which == 0) ? qb : (which == 1) ? kb : vb;
    const float qscale = (which == 0) ? 0.17677669529663689f : 1.0f;
#pragma unroll
    for (int mt = 0; mt < 2; ++mt) {
#pragma unroll
        for (int r = 0; r < 4; ++r) {
            const int m = m0 + mt * 16 + quad * 4 + r;
            const int b = m >> 8, tok = m & 255;
#pragma unroll
            for (int c4 = 0; c4 < 6; ++c4) {
                const int rem = (cb & 1) * 96 + c4 * 16 + l15;   // 0..191
                const int h = rem >> 5, d = rem & 31;
                const float val = (acc[mt][c4][r] + qkv_b[which * DIM_C + rem]) * qscale;
                outp[((size_t)((b * NHEADS + h) * N_TOK + tok)) * HD + d] = f2bf(val);
            }
        }
    }
}

// ---------------------------------------------------------------------------
// Kernel 5: proj GEMM, no LDS, same deep-ILP structure.
//   grid 1024 = 8 xcd * 64 panel-groups * 2 col-blocks (96 cols)
// ---------------------------------------------------------------------------
__global__ __launch_bounds__(256) void proj_gemm_kernel(
    const short* __restrict__ A16, const short* __restrict__ w16,
    const float* __restrict__ proj_b, float* __restrict__ out)
{
    const int t = threadIdx.x;
    const int lane = t & 63;
    const int w = t >> 6;
    const int l15 = lane & 15, quad = lane >> 4;

    const int l = blockIdx.x;            // 0..1023
    const int xcd = l & 7;
    const int s = l >> 3;                // 0..127
    const int cb = s % 2;                // col-block 0..1 (96 cols each)
    const int panel = xcd + 8 * (s / 2); // 0..511
    const int m0 = panel * 128 + w * 32;
    const int n0 = cb * 96;

    bf16x8 af[2][6];
#pragma unroll
    for (int mt = 0; mt < 2; ++mt)
#pragma unroll
        for (int ks = 0; ks < 6; ++ks)
            af[mt][ks] = *(const bf16x8*)(A16 + (size_t)(m0 + mt * 16 + l15) * DIM_C + ks * 32 + quad * 8);

    bf16x8 wb[2][6];
#pragma unroll
    for (int c4 = 0; c4 < 6; ++c4)
        wb[0][c4] = *(const bf16x8*)(w16 + (size_t)(n0 + c4 * 16 + l15) * DIM_C + quad * 8);

    f32x4 acc[2][6] = {};
#pragma unroll
    for (int ks = 0; ks < 6; ++ks) {
        if (ks < 5) {
#pragma unroll
            for (int c4 = 0; c4 < 6; ++c4)
                wb[(ks + 1) & 1][c4] = *(const bf16x8*)(w16 + (size_t)(n0 + c4 * 16 + l15) * DIM_C + (ks + 1) * 32 + quad * 8);
        }
#pragma unroll
        for (int mt = 0; mt < 2; ++mt)
#pragma unroll
            for (int c4 = 0; c4 < 6; ++c4)
                acc[mt][c4] = __builtin_amdgcn_mfma_f32_16x16x32_bf16(af[mt][ks], wb[ks & 1][c4], acc[mt][c4], 0, 0, 0);
    }

#pragma unroll
    for (int mt = 0; mt < 2; ++mt) {
#pragma unroll
        for (int r = 0; r < 4; ++r) {
            const int m = m0 + mt * 16 + quad * 4 + r;
#pragma unroll
            for (int c4 = 0; c4 < 6; ++c4) {
                const int c = n0 + c4 * 16 + l15;
                out[(size_t)m * DIM_C + c] = acc[mt][c4][r] + proj_b[c];
            }
        }
    }
}

// ---------------------------------------------------------------------------
// Kernel 4: MFMA attention per (b,h), wave-owns-rows structure.
//  - 1D grid + XCD-aware swizzle: all 24 blocks sharing a mask slab (bw)
//    run consecutively on one XCD.
//  - K fragments hoisted into registers once per block (chunk-invariant).
//  - bias+mask fed as the MFMA C operand (pre-permuted tables).
// ---------------------------------------------------------------------------
#define PS_LD 264   // shorts; 528 B/row (16B aligned)

__global__ __launch_bounds__(256, 3) void attn_mfma_kernel(
    const short* __restrict__ q, const short* __restrict__ k,
    const short* __restrict__ v, const short* __restrict__ bias_p,
    const short* __restrict__ mask_p, short* __restrict__ out16)
{
    __shared__ __align__(16) short Vt[32][PS_LD];      // V^T, 16.9 KB
    __shared__ __align__(16) short Pw[4][16][PS_LD];   // per-wave P, 33.8 KB

    // XCD-aware swizzle (bijective on 1536 = 8 xcd * 8 bw-groups * 24 jobs)
    const int l = blockIdx.x;            // 0..1535
    const int s = l >> 3;                // 0..191
    const int bw = (l & 7) + 8 * (s / 24);
    const int j = s % 24;
    const int h = j % 6;                 // 0..5
    const int b = (j / 6) * 64 + bw;     // 0..255

    const int t = threadIdx.x;
    const int lane = t & 63;
    const int w = t >> 6;
    const int l15 = lane & 15;
    const int quad = lane >> 4;
    const size_t slab = ((size_t)(b * NHEADS + h)) * (N_TOK * HD);

    // stage V^T (thread t -> token t), swizzled columns
    {
        const bf16x8* vrow = (const bf16x8*)(v + slab + (size_t)t * HD);
#pragma unroll
        for (int u = 0; u < 4; ++u) {
            bf16x8 vv = vrow[u];
#pragma unroll
            for (int jj = 0; jj < 8; ++jj) {
                const int d = u * 8 + jj;
                Vt[d][t ^ (((d >> 3) & 1) * 16)] = vv[jj];
            }
        }
    }

    // K fragments: chunk-invariant, load once (16 x bf16x8 = 64 VGPRs)
    bf16x8 kfr[16];
#pragma unroll
    for (int nt = 0; nt < 16; ++nt)
        kfr[nt] = *(const bf16x8*)(k + slab + (size_t)(nt * 16 + l15) * HD + quad * 8);

    __syncthreads();   // Vt ready (only barrier in the kernel body)

    const short* bslab = bias_p + h * 65536;
    const short* mslab = mask_p + bw * 65536;

    for (int chunk = 0; chunk < 4; ++chunk) {
        const int rb = chunk * 4 + w;    // row block 0..15

        // Q fragment: rows rb*16 + l15, k = quad*8..+7
        const bf16x8 qf = *(const bf16x8*)(q + slab + (size_t)(rb * 16 + l15) * HD + quad * 8);

        // QK^T with bias+mask injected as C:
        // C-layout: row = rb*16+quad*4+r, col = nt*16+l15
        f32x4 S[16];
#pragma unroll
        for (int half = 0; half < 2; ++half) {
            bf16x8 bb[4], mm[4];
#pragma unroll
            for (int gg = 0; gg < 4; ++gg) {
                const int g = half * 4 + gg;
                const int off = ((rb * 8 + g) * 64 + lane) * 8;
                bb[gg] = *(const bf16x8*)(bslab + off);
                mm[gg] = *(const bf16x8*)(mslab + off);
            }
#pragma unroll
            for (int gg = 0; gg < 4; ++gg) {
                const int g = half * 4 + gg;
                f32x4 c0, c1;
#pragma unroll
                for (int r = 0; r < 4; ++r) {
                    c0[r] = bf2f(bb[gg][r])     + bf2f(mm[gg][r]);
                    c1[r] = bf2f(bb[gg][4 + r]) + bf2f(mm[gg][4 + r]);
                }
                S[g * 2]     = __builtin_amdgcn_mfma_f32_16x16x32_bf16(qf, kfr[g * 2],     c0, 0, 0, 0);
                S[g * 2 + 1] = __builtin_amdgcn_mfma_f32_16x16x32_bf16(qf, kfr[g * 2 + 1], c1, 0, 0, 0);
            }
        }

        // row max over register tiles, then across l15 lanes
        float mx[4] = {-1e30f, -1e30f, -1e30f, -1e30f};
#pragma unroll
        for (int nt = 0; nt < 16; ++nt)
#pragma unroll
            for (int r = 0; r < 4; ++r)
                mx[r] = fmaxf(mx[r], S[nt][r]);
#pragma unroll
        for (int r = 0; r < 4; ++r) {
            mx[r] = fmaxf(mx[r], __shfl_xor(mx[r], 1));
            mx[r] = fmaxf(mx[r], __shfl_xor(mx[r], 2));
            mx[r] = fmaxf(mx[r], __shfl_xor(mx[r], 4));
            mx[r] = fmaxf(mx[r], __shfl_xor(mx[r], 8));
        }

        // exp + row sum + P -> per-wave LDS (swizzled)
        float sm[4] = {0.f, 0.f, 0.f, 0.f};
#pragma unroll
        for (int nt = 0; nt < 16; ++nt) {
#pragma unroll
            for (int r = 0; r < 4; ++r) {
                const float p = __expf(S[nt][r] - mx[r]);
                sm[r] += p;
                const int lr = quad * 4 + r;
                Pw[w][lr][(nt * 16 + l15) ^ (((lr >> 3) & 1) * 16)] = f2bf_fast(p);
            }
        }
        float inv[4];
#pragma unroll
        for (int r = 0; r < 4; ++r) {
            sm[r] += __shfl_xor(sm[r], 1);
            sm[r] += __shfl_xor(sm[r], 2);
            sm[r] += __shfl_xor(sm[r], 4);
            sm[r] += __shfl_xor(sm[r], 8);
            inv[r] = __builtin_amdgcn_rcpf(sm[r]);
        }

        // wave-local LDS: drain writes before fragment reads
        __asm__ volatile("s_waitcnt lgkmcnt(0)" ::: "memory");

        // PV: O (16 rows x 32 d), A-frags from own Pw, B-frags from Vt
        f32x4 O0 = {0.f, 0.f, 0.f, 0.f};
        f32x4 O1 = {0.f, 0.f, 0.f, 0.f};
        const int sw = ((l15 >> 3) & 1) * 16;
#pragma unroll
        for (int ks = 0; ks < 8; ++ks) {
            const int cb = ks * 32 + quad * 8;
            bf16x8 af  = *(const bf16x8*)&Pw[w][l15][cb ^ sw];
            bf16x8 bf0 = *(const bf16x8*)&Vt[l15][cb ^ sw];
            bf16x8 bf1 = *(const bf16x8*)&Vt[16 + l15][cb ^ sw];
            O0 = __builtin_amdgcn_mfma_f32_16x16x32_bf16(af, bf0, O0, 0, 0, 0);
            O1 = __builtin_amdgcn_mfma_f32_16x16x32_bf16(af, bf1, O1, 0, 0, 0);
        }

        // epilogue: rows quad*4+r match this thread's inv[r]
#pragma unroll
        for (int r = 0; r < 4; ++r) {
            const int token = rb * 16 + quad * 4 + r;
            short* dst = out16 + ((size_t)(b * N_TOK + token)) * DIM_C + h * HD;
            dst[l15]      = f2bf_fast(O0[r] * inv[r]);
            dst[16 + l15] = f2bf_fast(O1[r] * inv[r]);
        }
    }
}

// ---------------------------------------------------------------------------
// Launch
// ---------------------------------------------------------------------------
extern "C" void kernel_launch(void* const* d_in, const int* in_sizes, int n_in,
                              void* d_out, int out_size, void* d_ws, size_t ws_size,
                              hipStream_t stream)
{
    const float* x      = (const float*)d_in[0];   // (256,256,192)
    const float* scale  = (const float*)d_in[1];   // (1,2)
    const float* mask   = (const float*)d_in[2];   // (64,256,256)
    const float* qkv_w  = (const float*)d_in[3];   // (576,192)
    const float* qkv_b  = (const float*)d_in[4];   // (576,)
    const float* cpb_w1 = (const float*)d_in[5];   // (512,4)
    const float* cpb_b1 = (const float*)d_in[6];   // (512,)
    const float* cpb_w2 = (const float*)d_in[7];   // (6,512)
    const float* cpb_b2 = (const float*)d_in[8];   // (6,)
    const float* proj_w = (const float*)d_in[9];   // (192,192)
    const float* proj_b = (const float*)d_in[10];  // (192,)
    float* out = (float*)d_out;                    // (256,256,192) fp32

    const size_t per = (size_t)B_WIN * NHEADS * N_TOK * HD;  // 12,582,912
    short* wss     = (short*)d_ws;
    short* qb      = wss;
    short* kb      = qb + per;
    short* vb      = kb + per;
    short* ao      = vb + per;
    short* x16     = ao + per;                    // 12,582,912
    short* bias_p  = x16 + per;                   // 6*65536  =   393,216
    short* mask_p  = bias_p + 393216;             // 64*65536 = 4,194,304
    short* qkvw16  = mask_p + 4194304;            // 110,592
    short* projw16 = qkvw16 + 110592;             // 36,864
    float* table   = (float*)(projw16 + 36864);   // 961*6 fp32

    cpb_table_kernel<<<961, 512, 0, stream>>>(scale, cpb_w1, cpb_b1, cpb_w2, cpb_b2, table);

    bias_perm_kernel<<<(NHEADS * 8192) / 256, 256, 0, stream>>>(table, bias_p);
    mask_perm_kernel<<<(64 * 8192) / 256, 256, 0, stream>>>(mask, mask_p);

    f32_to_bf16_kernel<<<(int)((per / 4 + 255) / 256), 256, 0, stream>>>(x, x16, (int)(per / 4));
    f32_to_bf16_kernel<<<(110592 / 4 + 255) / 256, 256, 0, stream>>>(qkv_w, qkvw16, 110592 / 4);
    f32_to_bf16_kernel<<<(36864 / 4 + 255) / 256, 256, 0, stream>>>(proj_w, projw16, 36864 / 4);

    qkv_gemm_kernel<<<3072, 256, 0, stream>>>(x16, qkvw16, qkv_b, qb, kb, vb);

    attn_mfma_kernel<<<NHEADS * B_WIN, 256, 0, stream>>>(qb, kb, vb, bias_p, mask_p, ao);

    proj_gemm_kernel<<<1024, 256, 0, stream>>>(ao, projw16, proj_b, out);
}

// Round 7
// 312.018 us; speedup vs baseline: 1.1775x; 1.0206x over previous
//
#include <hip/hip_runtime.h>
#include <math.h>

// Problem constants:
//   WH=WW=16, N=256 tokens/window, H=6 heads, DIM=192, hd=32
//   B_=256 windows, nW=64 mask windows, qk_scale = 32^-0.5
#define N_TOK 256
#define NHEADS 6
#define DIM_C 192
#define HD 32
#define B_WIN 256

typedef short bf16x8 __attribute__((ext_vector_type(8)));   // 8 bf16 in 4 VGPRs
typedef float f32x4 __attribute__((ext_vector_type(4)));

__device__ inline short f2bf(float f) {          // RNE
    unsigned u = __float_as_uint(f);
    u = (u + 0x7fffu + ((u >> 16) & 1u)) >> 16;
    return (short)u;
}
__device__ inline short f2bf_fast(float f) {     // round-half-up (0.5 ulp)
    return (short)((__float_as_uint(f) + 0x8000u) >> 16);
}
__device__ inline float bf2f(short s) {
    return __uint_as_float(((unsigned)(unsigned short)s) << 16);
}
// packed RNE f32x2 -> bf16x2 (one VALU op)
__device__ inline unsigned cvt_pk_bf16(float lo, float hi) {
    unsigned r;
    asm("v_cvt_pk_bf16_f32 %0, %1, %2" : "=v"(r) : "v"(lo), "v"(hi));
    return r;
}

// ---------------------------------------------------------------------------
// Kernel 1: CPB MLP -> table (961 x 6) fp32
// ---------------------------------------------------------------------------
__global__ __launch_bounds__(512) void cpb_table_kernel(
    const float* __restrict__ scale, const float* __restrict__ w1,
    const float* __restrict__ b1, const float* __restrict__ w2,
    const float* __restrict__ b2, float* __restrict__ table)
{
    __shared__ float red[512];
    const int e = blockIdx.x;            // 0..960
    const int i = e / 31, j = e % 31;
    const float t0 = ((float)(i - 15)) * (8.0f / 15.0f);
    const float t1 = ((float)(j - 15)) * (8.0f / 15.0f);
    const float s0 = scale[0], s1 = scale[1];
    const int t = threadIdx.x;
    const float* w = w1 + t * 4;
    float h = w[0] * t0 + w[1] * t1 + w[2] * s0 + w[3] * s1 + b1[t];
    h = fmaxf(h, 0.0f);
    for (int head = 0; head < NHEADS; ++head) {
        red[t] = h * w2[head * 512 + t];
        __syncthreads();
        for (int s = 256; s > 0; s >>= 1) {
            if (t < s) red[t] += red[t + s];
            __syncthreads();
        }
        if (t == 0) table[e * NHEADS + head] = red[0] + b2[head];
        __syncthreads();
    }
}

// ---------------------------------------------------------------------------
// TRANSPOSED perm layout (for swapped QK^T: S^T = mfma(K, Q, C)).
// Slab (65536 bf16): offset = ((rb*8 + g)*64 + lane)*8 + (nt&1)*4 + r
//   value = src[q = rb*16 + (lane&15)][k = nt*16 + (lane>>4)*4 + r]
//   nt = 2g + (j>>2), r = j&3 for thread-j of 8.
// ---------------------------------------------------------------------------

// Kernel 2a: bias -> transposed-perm bf16 (6 slabs).
__global__ __launch_bounds__(256) void bias_perm_kernel(
    const float* __restrict__ table, short* __restrict__ bias_p)
{
    const int idx8 = blockIdx.x * 256 + threadIdx.x;   // < 6*8192
    const int h = idx8 >> 13;
    const int rem = idx8 & 8191;
    const int rb = rem >> 9;
    const int g = (rem >> 6) & 7;
    const int lane = rem & 63;
    const int quad = lane >> 4, l15 = lane & 15;
    bf16x8 o;
#pragma unroll
    for (int j = 0; j < 8; ++j) {
        const int nt = g * 2 + (j >> 2), r = j & 3;
        const int rel0 = rb - nt + 15;                       // (q>>4)-(k>>4)+15
        const int rel1 = l15 - (quad * 4 + r) + 15;          // (q&15)-(k&15)+15
        o[j] = f2bf(table[(rel0 * 31 + rel1) * NHEADS + h]);
    }
    ((bf16x8*)bias_p)[idx8] = o;
}

// Kernel 2b: mask -> transposed-perm bf16 (64 slabs).
__global__ __launch_bounds__(256) void mask_perm_kernel(
    const float* __restrict__ mask, short* __restrict__ mask_p)
{
    const int idx8 = blockIdx.x * 256 + threadIdx.x;   // < 64*8192
    const int bw = idx8 >> 13;
    const int rem = idx8 & 8191;
    const int rb = rem >> 9;
    const int g = (rem >> 6) & 7;
    const int lane = rem & 63;
    const int quad = lane >> 4, l15 = lane & 15;
    const float* ms = mask + ((size_t)bw << 16);
    bf16x8 o;
#pragma unroll
    for (int j = 0; j < 8; ++j) {
        const int nt = g * 2 + (j >> 2), r = j & 3;
        const int q = rb * 16 + l15;
        const int k = nt * 16 + quad * 4 + r;
        o[j] = f2bf(ms[q * 256 + k]);
    }
    ((bf16x8*)mask_p)[idx8] = o;
}

// ---------------------------------------------------------------------------
// Kernel 2c: generic fp32 -> bf16 (n4 = count/4)
// ---------------------------------------------------------------------------
__global__ __launch_bounds__(256) void f32_to_bf16_kernel(
    const float* __restrict__ in, short* __restrict__ out, int n4)
{
    const int i = blockIdx.x * 256 + threadIdx.x;
    if (i < n4) {
        float4 v = ((const float4*)in)[i];
        short4 s;
        s.x = f2bf(v.x); s.y = f2bf(v.y); s.z = f2bf(v.z); s.w = f2bf(v.w);
        ((short4*)out)[i] = s;
    }
}

// ---------------------------------------------------------------------------
// Kernel 3: QKV GEMM, no LDS, deep-ILP (R6 structure, kept).
// Grid 3072 = 8 xcd * 64 panel-groups * 6 col-blocks (96 cols each).
// ---------------------------------------------------------------------------
__global__ __launch_bounds__(256) void qkv_gemm_kernel(
    const short* __restrict__ x16, const short* __restrict__ w16,
    const float* __restrict__ qkv_b,
    short* __restrict__ qb, short* __restrict__ kb, short* __restrict__ vb)
{
    const int t = threadIdx.x;
    const int lane = t & 63;
    const int w = t >> 6;
    const int l15 = lane & 15, quad = lane >> 4;

    const int l = blockIdx.x;            // 0..3071
    const int xcd = l & 7;
    const int s = l >> 3;                // 0..383
    const int cb = s % 6;                // col-block 0..5 (96 cols each)
    const int panel = xcd + 8 * (s / 6); // 0..511
    const int m0 = panel * 128 + w * 32;
    const int n0 = cb * 96;

    // preload ALL A fragments: af[mt][ks] (12 x b128), independent
    bf16x8 af[2][6];
#pragma unroll
    for (int mt = 0; mt < 2; ++mt)
#pragma unroll
        for (int ks = 0; ks < 6; ++ks)
            af[mt][ks] = *(const bf16x8*)(x16 + (size_t)(m0 + mt * 16 + l15) * DIM_C + ks * 32 + quad * 8);

    // W double buffer: prime ks=0
    bf16x8 wb[2][6];
#pragma unroll
    for (int c4 = 0; c4 < 6; ++c4)
        wb[0][c4] = *(const bf16x8*)(w16 + (size_t)(n0 + c4 * 16 + l15) * DIM_C + quad * 8);

    f32x4 acc[2][6] = {};
#pragma unroll
    for (int ks = 0; ks < 6; ++ks) {
        if (ks < 5) {
#pragma unroll
            for (int c4 = 0; c4 < 6; ++c4)
                wb[(ks + 1) & 1][c4] = *(const bf16x8*)(w16 + (size_t)(n0 + c4 * 16 + l15) * DIM_C + (ks + 1) * 32 + quad * 8);
        }
#pragma unroll
        for (int mt = 0; mt < 2; ++mt)
#pragma unroll
            for (int c4 = 0; c4 < 6; ++c4)
                acc[mt][c4] = __builtin_amdgcn_mfma_f32_16x16x32_bf16(af[mt][ks], wb[ks & 1][c4], acc[mt][c4], 0, 0, 0);
    }

    const int which = cb >> 1;           // 0=q,1=k,2=v (constant per block)
    short* outp = (which == 0) ? qb : (which == 1) ? kb : vb;
    const float qscale = (which == 0) ? 0.17677669529663689f : 1.0f;
#pragma unroll
    for (int mt = 0; mt < 2; ++mt) {
#pragma unroll
        for (int r = 0; r < 4; ++r) {
            const int m = m0 + mt * 16 + quad * 4 + r;
            const int b = m >> 8, tok = m & 255;
#pragma unroll
            for (int c4 = 0; c4 < 6; ++c4) {
                const int rem = (cb & 1) * 96 + c4 * 16 + l15;   // 0..191
                const int h = rem >> 5, d = rem & 31;
                const float val = (acc[mt][c4][r] + qkv_b[which * DIM_C + rem]) * qscale;
                outp[((size_t)((b * NHEADS + h) * N_TOK + tok)) * HD + d] = f2bf(val);
            }
        }
    }
}

// ---------------------------------------------------------------------------
// Kernel 5: proj GEMM, no LDS, deep-ILP (R6 structure, kept).
// ---------------------------------------------------------------------------
__global__ __launch_bounds__(256) void proj_gemm_kernel(
    const short* __restrict__ A16, const short* __restrict__ w16,
    const float* __restrict__ proj_b, float* __restrict__ out)
{
    const int t = threadIdx.x;
    const int lane = t & 63;
    const int w = t >> 6;
    const int l15 = lane & 15, quad = lane >> 4;

    const int l = blockIdx.x;            // 0..1023
    const int xcd = l & 7;
    const int s = l >> 3;                // 0..127
    const int cb = s % 2;                // col-block 0..1 (96 cols each)
    const int panel = xcd + 8 * (s / 2); // 0..511
    const int m0 = panel * 128 + w * 32;
    const int n0 = cb * 96;

    bf16x8 af[2][6];
#pragma unroll
    for (int mt = 0; mt < 2; ++mt)
#pragma unroll
        for (int ks = 0; ks < 6; ++ks)
            af[mt][ks] = *(const bf16x8*)(A16 + (size_t)(m0 + mt * 16 + l15) * DIM_C + ks * 32 + quad * 8);

    bf16x8 wb[2][6];
#pragma unroll
    for (int c4 = 0; c4 < 6; ++c4)
        wb[0][c4] = *(const bf16x8*)(w16 + (size_t)(n0 + c4 * 16 + l15) * DIM_C + quad * 8);

    f32x4 acc[2][6] = {};
#pragma unroll
    for (int ks = 0; ks < 6; ++ks) {
        if (ks < 5) {
#pragma unroll
            for (int c4 = 0; c4 < 6; ++c4)
                wb[(ks + 1) & 1][c4] = *(const bf16x8*)(w16 + (size_t)(n0 + c4 * 16 + l15) * DIM_C + (ks + 1) * 32 + quad * 8);
        }
#pragma unroll
        for (int mt = 0; mt < 2; ++mt)
#pragma unroll
            for (int c4 = 0; c4 < 6; ++c4)
                acc[mt][c4] = __builtin_amdgcn_mfma_f32_16x16x32_bf16(af[mt][ks], wb[ks & 1][c4], acc[mt][c4], 0, 0, 0);
    }

#pragma unroll
    for (int mt = 0; mt < 2; ++mt) {
#pragma unroll
        for (int r = 0; r < 4; ++r) {
            const int m = m0 + mt * 16 + quad * 4 + r;
#pragma unroll
            for (int c4 = 0; c4 < 6; ++c4) {
                const int c = n0 + c4 * 16 + l15;
                out[(size_t)m * DIM_C + c] = acc[mt][c4][r] + proj_b[c];
            }
        }
    }
}

// ---------------------------------------------------------------------------
// Kernel 4: MFMA attention, SWAPPED QK^T (T12 structure).
//   S_nt = mfma(K_nt, Q_rb, C^T)  ->  lane owns ONE q-row (q = rb*16+l15),
//   k = nt*16+quad*4+r. Softmax is per-lane + 2 shuffles; P packed with
//   v_cvt_pk_bf16_f32 and written as 16 b64 LDS writes per chunk (was 64
//   scalar b16). PV/Vt/stores unchanged; inv redistributed by 4 shfl.
// ---------------------------------------------------------------------------
#define PS_LD 264   // shorts; 528 B/row (16B aligned)

__global__ __launch_bounds__(256, 3) void attn_mfma_kernel(
    const short* __restrict__ q, const short* __restrict__ k,
    const short* __restrict__ v, const short* __restrict__ bias_p,
    const short* __restrict__ mask_p, short* __restrict__ out16)
{
    __shared__ __align__(16) short Vt[32][PS_LD];      // V^T, 16.9 KB
    __shared__ __align__(16) short Pw[4][16][PS_LD];   // per-wave P, 33.8 KB

    // XCD-aware swizzle (bijective on 1536 = 8 xcd * 8 bw-groups * 24 jobs)
    const int l = blockIdx.x;            // 0..1535
    const int s = l >> 3;                // 0..191
    const int bw = (l & 7) + 8 * (s / 24);
    const int j = s % 24;
    const int h = j % 6;                 // 0..5
    const int b = (j / 6) * 64 + bw;     // 0..255

    const int t = threadIdx.x;
    const int lane = t & 63;
    const int w = t >> 6;
    const int l15 = lane & 15;
    const int quad = lane >> 4;
    const size_t slab = ((size_t)(b * NHEADS + h)) * (N_TOK * HD);

    // stage V^T (thread t -> token t), swizzled columns
    {
        const bf16x8* vrow = (const bf16x8*)(v + slab + (size_t)t * HD);
#pragma unroll
        for (int u = 0; u < 4; ++u) {
            bf16x8 vv = vrow[u];
#pragma unroll
            for (int jj = 0; jj < 8; ++jj) {
                const int d = u * 8 + jj;
                Vt[d][t ^ (((d >> 3) & 1) * 16)] = vv[jj];
            }
        }
    }

    // K fragments: chunk-invariant, load once (16 x bf16x8 = 64 VGPRs)
    bf16x8 kfr[16];
#pragma unroll
    for (int nt = 0; nt < 16; ++nt)
        kfr[nt] = *(const bf16x8*)(k + slab + (size_t)(nt * 16 + l15) * HD + quad * 8);

    __syncthreads();   // Vt ready (only barrier in the kernel body)

    const short* bslab = bias_p + h * 65536;
    const short* mslab = mask_p + bw * 65536;
    const int sw = ((l15 >> 3) & 1) * 16;

    for (int chunk = 0; chunk < 4; ++chunk) {
        const int rb = chunk * 4 + w;    // row block 0..15

        // Q fragment: rows rb*16 + l15, d = quad*8..+7 (B-operand: col = q)
        const bf16x8 qf = *(const bf16x8*)(q + slab + (size_t)(rb * 16 + l15) * HD + quad * 8);

        // Swapped QK^T with transposed bias+mask injected as C:
        // S[nt][r] = S[q = rb*16+l15][k = nt*16+quad*4+r]
        f32x4 S[16];
#pragma unroll
        for (int half = 0; half < 2; ++half) {
            bf16x8 bb[4], mm[4];
#pragma unroll
            for (int gg = 0; gg < 4; ++gg) {
                const int g = half * 4 + gg;
                const int off = ((rb * 8 + g) * 64 + lane) * 8;
                bb[gg] = *(const bf16x8*)(bslab + off);
                mm[gg] = *(const bf16x8*)(mslab + off);
            }
#pragma unroll
            for (int gg = 0; gg < 4; ++gg) {
                const int g = half * 4 + gg;
                f32x4 c0, c1;
#pragma unroll
                for (int r = 0; r < 4; ++r) {
                    c0[r] = bf2f(bb[gg][r])     + bf2f(mm[gg][r]);
                    c1[r] = bf2f(bb[gg][4 + r]) + bf2f(mm[gg][4 + r]);
                }
                S[g * 2]     = __builtin_amdgcn_mfma_f32_16x16x32_bf16(kfr[g * 2],     qf, c0, 0, 0, 0);
                S[g * 2 + 1] = __builtin_amdgcn_mfma_f32_16x16x32_bf16(kfr[g * 2 + 1], qf, c1, 0, 0, 0);
            }
        }

        // row max: per-lane over 64 values (4 partial chains) + 2 shuffles
        float mxp[4] = {-1e30f, -1e30f, -1e30f, -1e30f};
#pragma unroll
        for (int nt = 0; nt < 16; ++nt)
#pragma unroll
            for (int r = 0; r < 4; ++r)
                mxp[r] = fmaxf(mxp[r], S[nt][r]);
        float mx = fmaxf(fmaxf(mxp[0], mxp[1]), fmaxf(mxp[2], mxp[3]));
        mx = fmaxf(mx, __shfl_xor(mx, 16));
        mx = fmaxf(mx, __shfl_xor(mx, 32));

        // exp + sum + packed P -> per-wave LDS (b64 writes, swizzled)
        float sm[4] = {0.f, 0.f, 0.f, 0.f};
        short* prow = &Pw[w][l15][0];
#pragma unroll
        for (int nt = 0; nt < 16; ++nt) {
            const float p0 = __expf(S[nt][0] - mx);
            const float p1 = __expf(S[nt][1] - mx);
            const float p2 = __expf(S[nt][2] - mx);
            const float p3 = __expf(S[nt][3] - mx);
            sm[0] += p0; sm[1] += p1; sm[2] += p2; sm[3] += p3;
            uint2 pk;
            pk.x = cvt_pk_bf16(p0, p1);
            pk.y = cvt_pk_bf16(p2, p3);
            *(uint2*)&prow[(nt * 16 + quad * 4) ^ sw] = pk;
        }
        float smt = (sm[0] + sm[1]) + (sm[2] + sm[3]);
        smt += __shfl_xor(smt, 16);
        smt += __shfl_xor(smt, 32);
        const float inv = __builtin_amdgcn_rcpf(smt);

        // wave-local LDS: drain writes before fragment reads
        __asm__ volatile("s_waitcnt lgkmcnt(0)" ::: "memory");

        // PV: O (16 rows x 32 d), A-frags from own Pw, B-frags from Vt
        f32x4 O0 = {0.f, 0.f, 0.f, 0.f};
        f32x4 O1 = {0.f, 0.f, 0.f, 0.f};
#pragma unroll
        for (int ks = 0; ks < 8; ++ks) {
            const int cb = ks * 32 + quad * 8;
            bf16x8 af  = *(const bf16x8*)&Pw[w][l15][cb ^ sw];
            bf16x8 bf0 = *(const bf16x8*)&Vt[l15][cb ^ sw];
            bf16x8 bf1 = *(const bf16x8*)&Vt[16 + l15][cb ^ sw];
            O0 = __builtin_amdgcn_mfma_f32_16x16x32_bf16(af, bf0, O0, 0, 0, 0);
            O1 = __builtin_amdgcn_mfma_f32_16x16x32_bf16(af, bf1, O1, 0, 0, 0);
        }

        // epilogue: output rows are quad*4+r; softmax inv lives at lane l15=q
        float inv_e[4];
#pragma unroll
        for (int r = 0; r < 4; ++r)
            inv_e[r] = __shfl(inv, quad * 4 + r);
#pragma unroll
        for (int r = 0; r < 4; ++r) {
            const int token = rb * 16 + quad * 4 + r;
            short* dst = out16 + ((size_t)(b * N_TOK + token)) * DIM_C + h * HD;
            dst[l15]      = f2bf_fast(O0[r] * inv_e[r]);
            dst[16 + l15] = f2bf_fast(O1[r] * inv_e[r]);
        }
    }
}

// ---------------------------------------------------------------------------
// Launch
// ---------------------------------------------------------------------------
extern "C" void kernel_launch(void* const* d_in, const int* in_sizes, int n_in,
                              void* d_out, int out_size, void* d_ws, size_t ws_size,
                              hipStream_t stream)
{
    const float* x      = (const float*)d_in[0];   // (256,256,192)
    const float* scale  = (const float*)d_in[1];   // (1,2)
    const float* mask   = (const float*)d_in[2];   // (64,256,256)
    const float* qkv_w  = (const float*)d_in[3];   // (576,192)
    const float* qkv_b  = (const float*)d_in[4];   // (576,)
    const float* cpb_w1 = (const float*)d_in[5];   // (512,4)
    const float* cpb_b1 = (const float*)d_in[6];   // (512,)
    const float* cpb_w2 = (const float*)d_in[7];   // (6,512)
    const float* cpb_b2 = (const float*)d_in[8];   // (6,)
    const float* proj_w = (const float*)d_in[9];   // (192,192)
    const float* proj_b = (const float*)d_in[10];  // (192,)
    float* out = (float*)d_out;                    // (256,256,192) fp32

    const size_t per = (size_t)B_WIN * NHEADS * N_TOK * HD;  // 12,582,912
    short* wss     = (short*)d_ws;
    short* qb      = wss;
    short* kb      = qb + per;
    short* vb      = kb + per;
    short* ao      = vb + per;
    short* x16     = ao + per;                    // 12,582,912
    short* bias_p  = x16 + per;                   // 6*65536  =   393,216
    short* mask_p  = bias_p + 393216;             // 64*65536 = 4,194,304
    short* qkvw16  = mask_p + 4194304;            // 110,592
    short* projw16 = qkvw16 + 110592;             // 36,864
    float* table   = (float*)(projw16 + 36864);   // 961*6 fp32

    cpb_table_kernel<<<961, 512, 0, stream>>>(scale, cpb_w1, cpb_b1, cpb_w2, cpb_b2, table);

    bias_perm_kernel<<<(NHEADS * 8192) / 256, 256, 0, stream>>>(table, bias_p);
    mask_perm_kernel<<<(64 * 8192) / 256, 256, 0, stream>>>(mask, mask_p);

    f32_to_bf16_kernel<<<(int)((per / 4 + 255) / 256), 256, 0, stream>>>(x, x16, (int)(per / 4));
    f32_to_bf16_kernel<<<(110592 / 4 + 255) / 256, 256, 0, stream>>>(qkv_w, qkvw16, 110592 / 4);
    f32_to_bf16_kernel<<<(36864 / 4 + 255) / 256, 256, 0, stream>>>(proj_w, projw16, 36864 / 4);

    qkv_gemm_kernel<<<3072, 256, 0, stream>>>(x16, qkvw16, qkv_b, qb, kb, vb);

    attn_mfma_kernel<<<NHEADS * B_WIN, 256, 0, stream>>>(qb, kb, vb, bias_p, mask_p, ao);

    proj_gemm_kernel<<<1024, 256, 0, stream>>>(ao, projw16, proj_b, out);
}